// Round 4
// baseline (539.294 us; speedup 1.0000x reference)
//
#include <hip/hip_runtime.h>
#include <math.h>

// ---------------------------------------------------------------------------
// ws layout:
//   shorts @0: repW2 393216, repW3 @393216 (442368), repR1 @835584 (110592),
//              repR2 @946176 (110592), repP1 @1056768 (12288), repP2 @1069056
//   floats:  B @4194304 : conv2 out / h' [16,128,64,64]
//            A @12582912: conv1 half-out [8,64,128,128] -> h [16,128,64,64]
// Flow: conv1->A, conv2 A->B (x2 halves); conv3 B->A; res1 A->B; res2 B->A;
//       prevq A->out.
//
// Round 4: multi-row blocking (OYB output rows per block) for conv3 and res.
//   Rationale (R0-R3 counters): MfmaUtil pinned at 53-58% across three
//   schedule variants -> gap is per-output-row overhead (B-fragment L2
//   re-fetch ~864KB/row, 3-row staging, 8 barriers/row), not LDS or barriers.
//   OYB=2 halves B traffic+issue, cuts staging/row 3->2, halves barriers,
//   keeps per-output MFMA order bit-identical. conv2 keeps OYB=1 (n=8 grid
//   would drop to 1 block/CU otherwise -> no cross-block hiding).
// ---------------------------------------------------------------------------

typedef short v8s __attribute__((ext_vector_type(8)));
typedef float v4f __attribute__((ext_vector_type(4)));

#define B_OFF 4194304
#define A_OFF 12582912
#define W2_S 0
#define W3_S 393216
#define WR1_S 835584
#define WR2_S 946176
#define WP1_S 1056768
#define WP2_S 1069056

// 3-limb bf16 truncation decomposition: x = h+m+l + O(2^-24 |x|)
__device__ inline void limb3(float v, unsigned short& h, unsigned short& m,
                             unsigned short& l) {
    unsigned ub = __float_as_uint(v);
    unsigned hb = ub & 0xffff0000u;
    float r1 = v - __uint_as_float(hb);
    unsigned mb = __float_as_uint(r1) & 0xffff0000u;
    float r2 = r1 - __uint_as_float(mb);
    unsigned lb = __float_as_uint(r2) & 0xffff0000u;
    h = (unsigned short)(hb >> 16);
    m = (unsigned short)(mb >> 16);
    l = (unsigned short)(lb >> 16);
}

// ----- conv configs ---------------------------------------------------------
struct CfgConv2 {   // 4x4 s2 p1 as stride-1 conv over 4 phase planes
    static constexpr int NC = 8, NT = 4, OC = 128, ICG = 64, IN_H = 128, IN_W = 128;
    static constexpr int OYB = 1;
    static constexpr bool RELU_IN = false, RELU_OUT = true;
    __device__ static void tap(int c, int t, int& ry, int& rx) {
        int py = (c >> 2) & 1, px = (c >> 1) & 1;
        ry = (t >> 1) - py; rx = (t & 1) - px;
    }
    __device__ static void inaddr(int c, int oy0, int r, int X,
                                  int& Yg, int& Xg, int& ic0) {
        int py = (c >> 2) & 1, px = (c >> 1) & 1;
        Yg = 2 * (oy0 + r - 1) + py; Xg = 2 * X + px; ic0 = (c & 1) * 32;
    }
    __device__ static int widx(int c, int t, int oc, int ic) {
        int py = (c >> 2) & 1, px = (c >> 1) & 1, half = c & 1;
        int dy = 2 * (t >> 1) + (1 - py), dx = 2 * (t & 1) + (1 - px);
        return ((oc * 64 + half * 32 + ic) * 4 + dy) * 4 + dx;
    }
};
struct CfgConv3 {   // 3x3 s1 p1, 128->128, 2 output rows per block
    static constexpr int NC = 4, NT = 9, OC = 128, ICG = 128, IN_H = 64, IN_W = 64;
    static constexpr int OYB = 2;
    static constexpr bool RELU_IN = false, RELU_OUT = false;
    __device__ static void tap(int c, int t, int& ry, int& rx) {
        ry = t / 3 - 1; rx = t % 3 - 1;
    }
    __device__ static void inaddr(int c, int oy0, int r, int X,
                                  int& Yg, int& Xg, int& ic0) {
        Yg = oy0 + r - 1; Xg = X; ic0 = c * 32;
    }
    __device__ static int widx(int c, int t, int oc, int ic) {
        return ((oc * 128 + c * 32 + ic) * 3 + t / 3) * 3 + t % 3;
    }
};
struct CfgRes {     // 3x3 s1 p1, relu(in), 128->32
    static constexpr int NC = 4, NT = 9, OC = 32, ICG = 128, IN_H = 64, IN_W = 64;
    __device__ static int widx(int c, int t, int oc, int ic) {
        return ((oc * 128 + c * 32 + ic) * 3 + t / 3) * 3 + t % 3;
    }
};
struct Cfg1x1 {     // 1x1, 32->128
    static constexpr int NC = 1, NT = 1, OC = 128;
    __device__ static int widx(int c, int t, int oc, int ic) {
        return oc * 32 + ic;
    }
};

// ----- weight repack: fp32 -> per-lane B-fragment limb layout ---------------
// dst[(((ct*3+L)*NTILE + nt)<<9) + lane*8 + j], lane=q*16+o, oc=nt*16+o, ic=q*8+j
template <typename C>
__device__ inline void repack_one(const float* __restrict__ w,
                                  short* __restrict__ dst, int idx) {
    int s  = idx & 31;
    int oc = (idx >> 5) % C::OC;
    int ct = idx / (32 * C::OC);
    int c = ct / C::NT, t = ct % C::NT;
    float val = w[C::widx(c, t, oc, s)];
    unsigned short h, m, l;
    limb3(val, h, m, l);
    constexpr int NTILE = C::OC / 16;
    int nt = oc >> 4, o = oc & 15, q = s >> 3, j = s & 7;
    int fr = ((q * 16 + o) << 3) + j;
    dst[(((ct * 3 + 0) * NTILE + nt) << 9) + fr] = (short)h;
    dst[(((ct * 3 + 1) * NTILE + nt) << 9) + fr] = (short)m;
    dst[(((ct * 3 + 2) * NTILE + nt) << 9) + fr] = (short)l;
}

__global__ __launch_bounds__(256) void repack_all_k(
    const float* __restrict__ w2, const float* __restrict__ w3,
    const float* __restrict__ r1, const float* __restrict__ r2,
    const float* __restrict__ p1, const float* __restrict__ p2,
    short* __restrict__ base)
{
    int idx = blockIdx.x * 256 + threadIdx.x;
    if (idx < 131072) { repack_one<CfgConv2>(w2, base + W2_S, idx); return; }
    idx -= 131072;
    if (idx < 147456) { repack_one<CfgConv3>(w3, base + W3_S, idx); return; }
    idx -= 147456;
    if (idx < 36864)  { repack_one<CfgRes>(r1, base + WR1_S, idx); return; }
    idx -= 36864;
    if (idx < 36864)  { repack_one<CfgRes>(r2, base + WR2_S, idx); return; }
    idx -= 36864;
    if (idx < 4096)   { repack_one<Cfg1x1>(p1, base + WP1_S, idx); return; }
    idx -= 4096;
    if (idx < 4096)   { repack_one<Cfg1x1>(p2, base + WP2_S, idx); }
}

// ----- MFMA implicit-GEMM conv, OYB output rows per block -------------------
// wave wv owns all 4 mt x-tiles and nt-tiles {2wv, 2wv+1} (proven R0 split).
template <typename C>
__global__ __launch_bounds__(256, 2) void mfma_conv(
    const float* __restrict__ in, const short* __restrict__ repw,
    const float* __restrict__ bias, float* __restrict__ out, int n0)
{
    constexpr int OYB     = C::OYB;
    constexpr int WR      = OYB + 2;            // input window rows
    constexpr int PLANE_D = WR * 66 * 16;       // dwords per limb plane
    constexpr int PLANE_S = 2 * PLANE_D;        // shorts per limb plane
    constexpr int NTILE   = C::OC / 16;
    constexpr int NTT     = C::NT;
    constexpr int NIT     = WR * 4;             // staging iters per chunk
    constexpr int ROWS    = 64 / OYB;           // row-groups per image
    __shared__ __align__(16) short lA[3 * PLANE_S];

    int tid = threadIdx.x;
    int lane = tid & 63, wv = tid >> 6;
    int n_img = blockIdx.x / ROWS;
    int oy0 = (blockIdx.x % ROWS) * OYB;

    // zero halo cells (col 0 and 65, all window rows, all limbs)
    for (int idx = tid; idx < 3 * WR * 2 * 16; idx += 256) {
        int plane = idx / (WR * 32);
        int rem = idx % (WR * 32);
        int rr = rem / 32;
        int hc = (rem >> 4) & 1;
        int d = idx & 15;
        ((unsigned*)lA)[plane * PLANE_D + (rr * 66 + hc * 65) * 16 + d] = 0;
    }

    int nbase = wv * 2;
    v4f acc[OYB][4][2] = {};
    int Xq = tid & 15, icp = tid >> 4, quad = lane >> 4;

    float pv[2 * NIT];
    auto issue_loads = [&](int c) {
#pragma unroll
        for (int it = 0; it < NIT; it++) {
            int r = it >> 2, xg = it & 3;
            int X = xg * 16 + Xq;
            int Yg, Xg, ic0;
            C::inaddr(c, oy0, r, X, Yg, Xg, ic0);
            float v0 = 0.f, v1 = 0.f;
            if (Yg >= 0 && Yg < C::IN_H) {
                int g = ((n_img * C::ICG + ic0 + 2 * icp) * C::IN_H + Yg) * C::IN_W + Xg;
                v0 = in[g];
                v1 = in[g + C::IN_H * C::IN_W];
            }
            pv[2 * it] = v0; pv[2 * it + 1] = v1;
        }
    };
    auto load_bf = [&](int c, int t, v8s (&dst)[2][3]) {
#pragma unroll
        for (int nt = 0; nt < 2; nt++)
#pragma unroll
            for (int L = 0; L < 3; L++)
                dst[nt][L] = *(const v8s*)(repw +
                    ((((c * NTT + t) * 3 + L) * NTILE + (nbase + nt)) << 9) +
                    (lane << 3));
    };

    issue_loads(0);

    for (int c = 0; c < C::NC; c++) {
        __syncthreads();   // prev chunk's readers done before lA overwrite
        // ---- consume pv -> lA limb planes ----
#pragma unroll
        for (int it = 0; it < NIT; it++) {
            int r = it >> 2, xg = it & 3;
            int X = xg * 16 + Xq;
            float v0 = pv[2 * it], v1 = pv[2 * it + 1];
            if constexpr (C::RELU_IN) { v0 = fmaxf(v0, 0.f); v1 = fmaxf(v1, 0.f); }
            unsigned short h0, m0, l0, h1, m1, l1;
            limb3(v0, h0, m0, l0);
            limb3(v1, h1, m1, l1);
            int cell = r * 66 + X + 1;
            int f = (cell + (cell >> 2)) & 3;
            int phys = (icp & 3) + 4 * (((icp >> 2) + f) & 3);
            unsigned* pa = (unsigned*)lA + cell * 16 + phys;
            pa[0]            = (unsigned)h0 | ((unsigned)h1 << 16);
            pa[PLANE_D]      = (unsigned)m0 | ((unsigned)m1 << 16);
            pa[2 * PLANE_D]  = (unsigned)l0 | ((unsigned)l1 << 16);
        }
        __syncthreads();   // lA staged
        if (c + 1 < C::NC) issue_loads(c + 1);   // prefetch next chunk

        v8s bf[2][2][3];
        load_bf(c, 0, bf[0]);
#pragma unroll
        for (int t = 0; t < NTT; t++) {
            if (t + 1 < NTT) load_bf(c, t + 1, bf[(t + 1) & 1]);
            int ry, rx;
            C::tap(c, t, ry, rx);
#pragma unroll
            for (int j = 0; j < OYB; j++) {
#pragma unroll
                for (int mt = 0; mt < 4; mt++) {
                    int x = mt * 16 + (lane & 15);
                    int cell = (j + ry + 1) * 66 + (x + rx + 1);
                    int f = (cell + (cell >> 2)) & 3;
                    int aa = cell * 32 + (((quad + f) & 3) << 3);
                    v8s ah = *(const v8s*)&lA[aa];
                    v8s am = *(const v8s*)&lA[PLANE_S + aa];
                    v8s al = *(const v8s*)&lA[2 * PLANE_S + aa];
#pragma unroll
                    for (int nt = 0; nt < 2; nt++) {
                        v4f a0 = acc[j][mt][nt];
                        a0 = __builtin_amdgcn_mfma_f32_16x16x32_bf16(ah, bf[t & 1][nt][0], a0, 0, 0, 0);
                        a0 = __builtin_amdgcn_mfma_f32_16x16x32_bf16(ah, bf[t & 1][nt][1], a0, 0, 0, 0);
                        a0 = __builtin_amdgcn_mfma_f32_16x16x32_bf16(am, bf[t & 1][nt][0], a0, 0, 0, 0);
                        a0 = __builtin_amdgcn_mfma_f32_16x16x32_bf16(am, bf[t & 1][nt][1], a0, 0, 0, 0);
                        a0 = __builtin_amdgcn_mfma_f32_16x16x32_bf16(ah, bf[t & 1][nt][2], a0, 0, 0, 0);
                        a0 = __builtin_amdgcn_mfma_f32_16x16x32_bf16(al, bf[t & 1][nt][0], a0, 0, 0, 0);
                        acc[j][mt][nt] = a0;
                    }
                }
            }
        }
    }
    // ---- epilogue: C/D layout col=lane&15 (oc), row=quad*4+reg (x) ----
#pragma unroll
    for (int j = 0; j < OYB; j++) {
#pragma unroll
        for (int mt = 0; mt < 4; mt++) {
            int x0 = mt * 16 + quad * 4;
#pragma unroll
            for (int nt = 0; nt < 2; nt++) {
                int oc = (nbase + nt) * 16 + (lane & 15);
                float bv = bias[oc];
                float v0 = acc[j][mt][nt][0] + bv;
                float v1 = acc[j][mt][nt][1] + bv;
                float v2 = acc[j][mt][nt][2] + bv;
                float v3 = acc[j][mt][nt][3] + bv;
                if constexpr (C::RELU_OUT) {
                    v0 = fmaxf(v0, 0.f); v1 = fmaxf(v1, 0.f);
                    v2 = fmaxf(v2, 0.f); v3 = fmaxf(v3, 0.f);
                }
                float4 o = make_float4(v0, v1, v2, v3);
                *(float4*)&out[(((n0 + n_img) * C::OC + oc) * 64 + (oy0 + j)) * 64 + x0] = o;
            }
        }
    }
}

// ----- fused residual block, 2 output rows per block ------------------------
// t = conv3x3(relu(h)) + b1 (128->32);  out = h + conv1x1(relu(t)) + b2
// block = (n, oy-pair). Stage 1: limb-MFMA conv over 4-row window; B-frags
// loaded once per tap, reused for both rows. Stage 2: per-row relu(t) limbs
// -> LDS (A-frag layout), GEMM-2 with B loaded once, reused across rows.
__global__ __launch_bounds__(256, 2) void mfma_res(
    const float* __restrict__ in, const short* __restrict__ repw,
    const float* __restrict__ b1, const short* __restrict__ repp,
    const float* __restrict__ b2, float* __restrict__ out)
{
    constexpr int PLANE_D = 4 * 66 * 16;   // 4224 dwords per limb plane
    constexpr int PLANE_S = 2 * PLANE_D;   // 8448 shorts
    __shared__ __align__(16) short lA[3 * PLANE_S];   // 50688 B

    int tid = threadIdx.x;
    int lane = tid & 63, wv = tid >> 6;
    int n_img = blockIdx.x >> 5;
    int oy0 = (blockIdx.x & 31) << 1;

    for (int idx = tid; idx < 3 * 4 * 2 * 16; idx += 256) {
        int plane = idx / 128;
        int rem = idx % 128;
        int rr = rem / 32;
        int hc = (rem >> 4) & 1;
        int d = idx & 15;
        ((unsigned*)lA)[plane * PLANE_D + (rr * 66 + hc * 65) * 16 + d] = 0;
    }

    v4f acc[2][2] = {};     // [j][nt]
    int Xq = tid & 15, icp = tid >> 4, quad = lane >> 4;

    float pv[32];
    auto issue_loads = [&](int c) {
#pragma unroll
        for (int it = 0; it < 16; it++) {
            int r = it >> 2, xg = it & 3;
            int X = xg * 16 + Xq;
            int Yg = oy0 + r - 1;
            float v0 = 0.f, v1 = 0.f;
            if (Yg >= 0 && Yg < 64) {
                int g = ((n_img * 128 + c * 32 + 2 * icp) * 64 + Yg) * 64 + X;
                v0 = in[g];
                v1 = in[g + 4096];
            }
            pv[2 * it] = v0; pv[2 * it + 1] = v1;
        }
    };

    issue_loads(0);

    for (int c = 0; c < 4; c++) {
        __syncthreads();
#pragma unroll
        for (int it = 0; it < 16; it++) {
            int r = it >> 2, xg = it & 3;
            int X = xg * 16 + Xq;
            float v0 = fmaxf(pv[2 * it], 0.f);       // relu(h)
            float v1 = fmaxf(pv[2 * it + 1], 0.f);
            unsigned short h0, m0, l0, h1, m1, l1;
            limb3(v0, h0, m0, l0);
            limb3(v1, h1, m1, l1);
            int cell = r * 66 + X + 1;
            int f = (cell + (cell >> 2)) & 3;
            int phys = (icp & 3) + 4 * (((icp >> 2) + f) & 3);
            unsigned* pa = (unsigned*)lA + cell * 16 + phys;
            pa[0]           = (unsigned)h0 | ((unsigned)h1 << 16);
            pa[PLANE_D]     = (unsigned)m0 | ((unsigned)m1 << 16);
            pa[2 * PLANE_D] = (unsigned)l0 | ((unsigned)l1 << 16);
        }
        __syncthreads();
        if (c + 1 < 4) issue_loads(c + 1);

        v8s bf[2][2][3];
        auto load_bf = [&](int t, v8s (&dst)[2][3]) {
#pragma unroll
            for (int nt = 0; nt < 2; nt++)
#pragma unroll
                for (int L = 0; L < 3; L++)
                    dst[nt][L] = *(const v8s*)(repw +
                        ((((c * 9 + t) * 3 + L) * 2 + nt) << 9) + (lane << 3));
        };
        load_bf(0, bf[0]);
#pragma unroll
        for (int t = 0; t < 9; t++) {
            if (t + 1 < 9) load_bf(t + 1, bf[(t + 1) & 1]);
            int ry = t / 3 - 1, rx = t % 3 - 1;
#pragma unroll
            for (int j = 0; j < 2; j++) {
                int x = wv * 16 + (lane & 15);
                int cell = (j + ry + 1) * 66 + (x + rx + 1);
                int f = (cell + (cell >> 2)) & 3;
                int aa = cell * 32 + (((quad + f) & 3) << 3);
                v8s ah = *(const v8s*)&lA[aa];
                v8s am = *(const v8s*)&lA[PLANE_S + aa];
                v8s al = *(const v8s*)&lA[2 * PLANE_S + aa];
#pragma unroll
                for (int nt = 0; nt < 2; nt++) {
                    v4f a0 = acc[j][nt];
                    a0 = __builtin_amdgcn_mfma_f32_16x16x32_bf16(ah, bf[t & 1][nt][0], a0, 0, 0, 0);
                    a0 = __builtin_amdgcn_mfma_f32_16x16x32_bf16(ah, bf[t & 1][nt][1], a0, 0, 0, 0);
                    a0 = __builtin_amdgcn_mfma_f32_16x16x32_bf16(am, bf[t & 1][nt][0], a0, 0, 0, 0);
                    a0 = __builtin_amdgcn_mfma_f32_16x16x32_bf16(am, bf[t & 1][nt][1], a0, 0, 0, 0);
                    a0 = __builtin_amdgcn_mfma_f32_16x16x32_bf16(ah, bf[t & 1][nt][2], a0, 0, 0, 0);
                    a0 = __builtin_amdgcn_mfma_f32_16x16x32_bf16(al, bf[t & 1][nt][0], a0, 0, 0, 0);
                    acc[j][nt] = a0;
                }
            }
        }
    }

    // ===== stage 2: relu(t+b1) limbs -> LDS (A-frag layout, cell=x) =====
    __syncthreads();   // all lA tap-readers done; reuse front of lA
#pragma unroll
    for (int j = 0; j < 2; j++) {
#pragma unroll
        for (int nt = 0; nt < 2; nt++) {
            int ic = nt * 16 + (lane & 15);     // t-channel = GEMM-2 k index
            int icp2 = ic >> 1, hilo = ic & 1;
            float bv = b1[ic];
#pragma unroll
            for (int r = 0; r < 4; r++) {
                int x = wv * 16 + quad * 4 + r;
                float v = fmaxf(acc[j][nt][r] + bv, 0.f);
                unsigned short h, m, l;
                limb3(v, h, m, l);
                int f = (x + (x >> 2)) & 3;
                int phys = (icp2 & 3) + 4 * (((icp2 >> 2) + f) & 3);
                int sa = x * 32 + phys * 2 + hilo;
                lA[j * 6144 + sa]        = (short)h;
                lA[j * 6144 + 2048 + sa] = (short)m;
                lA[j * 6144 + 4096 + sa] = (short)l;
            }
        }
    }
    __syncthreads();

    // GEMM-2: per row M=64 (x, mt=wv), N=128 (oc2, nt=0..7), K=32.
    // B fragments loaded once, reused for both rows.
    v4f a2[2][8] = {};
    v8s ah[2], am[2], al[2];
#pragma unroll
    for (int j = 0; j < 2; j++) {
        int x = wv * 16 + (lane & 15);
        int f = (x + (x >> 2)) & 3;
        int aa = x * 32 + (((quad + f) & 3) << 3);
        ah[j] = *(const v8s*)&lA[j * 6144 + aa];
        am[j] = *(const v8s*)&lA[j * 6144 + 2048 + aa];
        al[j] = *(const v8s*)&lA[j * 6144 + 4096 + aa];
    }
#pragma unroll
    for (int nt = 0; nt < 8; nt++) {
        v8s bh = *(const v8s*)(repp + ((0 * 8 + nt) << 9) + (lane << 3));
        v8s bm = *(const v8s*)(repp + ((1 * 8 + nt) << 9) + (lane << 3));
        v8s bl = *(const v8s*)(repp + ((2 * 8 + nt) << 9) + (lane << 3));
#pragma unroll
        for (int j = 0; j < 2; j++) {
            v4f a0 = a2[j][nt];
            a0 = __builtin_amdgcn_mfma_f32_16x16x32_bf16(ah[j], bh, a0, 0, 0, 0);
            a0 = __builtin_amdgcn_mfma_f32_16x16x32_bf16(ah[j], bm, a0, 0, 0, 0);
            a0 = __builtin_amdgcn_mfma_f32_16x16x32_bf16(am[j], bh, a0, 0, 0, 0);
            a0 = __builtin_amdgcn_mfma_f32_16x16x32_bf16(am[j], bm, a0, 0, 0, 0);
            a0 = __builtin_amdgcn_mfma_f32_16x16x32_bf16(ah[j], bl, a0, 0, 0, 0);
            a0 = __builtin_amdgcn_mfma_f32_16x16x32_bf16(al[j], bh, a0, 0, 0, 0);
            a2[j][nt] = a0;
        }
    }
    // epilogue: out = h + t2 + b2
#pragma unroll
    for (int j = 0; j < 2; j++) {
#pragma unroll
        for (int nt = 0; nt < 8; nt++) {
            int oc = nt * 16 + (lane & 15);
            int x0 = wv * 16 + quad * 4;
            int off = ((n_img * 128 + oc) * 64 + (oy0 + j)) * 64 + x0;
            float4 hv = *(const float4*)&in[off];
            float bv = b2[oc];
            float4 o = make_float4(hv.x + a2[j][nt][0] + bv, hv.y + a2[j][nt][1] + bv,
                                   hv.z + a2[j][nt][2] + bv, hv.w + a2[j][nt][3] + bv);
            *(float4*)&out[off] = o;
        }
    }
}

// ----- conv1: [8,1,256,256] -> [8,64,128,128], 4x4 s2 p1, relu (fp32) -------
__global__ __launch_bounds__(256) void conv1_k(
    const float* __restrict__ x, const float* __restrict__ w,
    const float* __restrict__ b, float* __restrict__ out)
{
    int tid = blockIdx.x * 256 + threadIdx.x;     // 131072
    int n   = tid >> 14;
    int rem = tid & 16383;
    int oy  = rem >> 7;
    int ox  = rem & 127;
    int iy0 = oy * 2 - 1, ix0 = ox * 2 - 1;
    const float* xb = x + n * 65536;
    float v[16];
#pragma unroll
    for (int ky = 0; ky < 4; ky++) {
#pragma unroll
        for (int kx = 0; kx < 4; kx++) {
            int iy = iy0 + ky, ix = ix0 + kx;
            bool ok = (iy >= 0) & (iy < 256) & (ix >= 0) & (ix < 256);
            v[ky * 4 + kx] = ok ? xb[iy * 256 + ix] : 0.f;
        }
    }
    int obase = (n * 64) * 16384 + (oy << 7) + ox;
    for (int oc = 0; oc < 64; oc++) {
        float acc = b[oc];
        const float* wp = w + oc * 16;
#pragma unroll
        for (int k = 0; k < 16; k++) acc = fmaf(v[k], wp[k], acc);
        out[obase + oc * 16384] = fmaxf(acc, 0.f);
    }
}

// ----- fused 1x1 projection + cosine VQ (fp32, proven) ----------------------
__global__ __launch_bounds__(256) void prevq_k(
    const float* __restrict__ h, const float* __restrict__ wpre,
    const float* __restrict__ bpre, const float* __restrict__ cb,
    float* __restrict__ out)
{
    __shared__ float4 en[2048];
    for (int i = threadIdx.x; i < 2048; i += 256) {
        float c0 = cb[i * 4 + 0], c1 = cb[i * 4 + 1];
        float c2 = cb[i * 4 + 2], c3 = cb[i * 4 + 3];
        float nrm = sqrtf(c0 * c0 + c1 * c1 + c2 * c2 + c3 * c3) + 1e-12f;
        en[i] = make_float4(c0 / nrm, c1 / nrm, c2 / nrm, c3 / nrm);
    }
    __syncthreads();

    int tid = blockIdx.x * 256 + threadIdx.x;     // 65536
    int n   = tid >> 12;
    int pos = tid & 4095;
    const float* hb = h + n * 128 * 4096 + pos;
    float z0 = bpre[0], z1 = bpre[1], z2 = bpre[2], z3 = bpre[3];
    for (int ic = 0; ic < 128; ic++) {
        float v = fmaxf(hb[ic * 4096], 0.f);
        z0 = fmaf(v, wpre[ic],       z0);
        z1 = fmaf(v, wpre[128 + ic], z1);
        z2 = fmaf(v, wpre[256 + ic], z2);
        z3 = fmaf(v, wpre[384 + ic], z3);
    }
    // argmax of cosine sim is invariant to positive scaling of z
    float best = -1e30f;
    int   bidx = 0;
    for (int k = 0; k < 2048; k++) {
        float4 e = en[k];
        float s = z0 * e.x + z1 * e.y + z2 * e.z + z3 * e.w;
        if (s > best) { best = s; bidx = k; }     // strict > = first max
    }
    const float* q = cb + bidx * 4;
    out[(n * 4 + 0) * 4096 + pos] = q[0];
    out[(n * 4 + 1) * 4096 + pos] = q[1];
    out[(n * 4 + 2) * 4096 + pos] = q[2];
    out[(n * 4 + 3) * 4096 + pos] = q[3];
}

extern "C" void kernel_launch(void* const* d_in, const int* in_sizes, int n_in,
                              void* d_out, int out_size, void* d_ws, size_t ws_size,
                              hipStream_t stream)
{
    const float* x    = (const float*)d_in[0];
    const float* w1   = (const float*)d_in[1];
    const float* b1   = (const float*)d_in[2];
    const float* w2   = (const float*)d_in[3];
    const float* b2   = (const float*)d_in[4];
    const float* w3   = (const float*)d_in[5];
    const float* b3   = (const float*)d_in[6];
    const float* r1w1 = (const float*)d_in[7];
    const float* r1b1 = (const float*)d_in[8];
    const float* r1w2 = (const float*)d_in[9];
    const float* r1b2 = (const float*)d_in[10];
    const float* r2w1 = (const float*)d_in[11];
    const float* r2b1 = (const float*)d_in[12];
    const float* r2w2 = (const float*)d_in[13];
    const float* r2b2 = (const float*)d_in[14];
    const float* wpre = (const float*)d_in[15];
    const float* bpre = (const float*)d_in[16];
    const float* cb   = (const float*)d_in[17];
    float* out = (float*)d_out;

    float* ws   = (float*)d_ws;
    short* wsS  = (short*)d_ws;
    float* B = ws + B_OFF;
    float* A = ws + A_OFF;

    // one merged repack for all 6 weight tensors
    repack_all_k<<<1408, 256, 0, stream>>>(w2, w3, r1w1, r2w1, r1w2, r2w2, wsS);

    // front end, batch split in halves ping-ponging through A
    conv1_k<<<512, 256, 0, stream>>>(x,               w1, b1, A);
    mfma_conv<CfgConv2><<<512, 256, 0, stream>>>(A, wsS + W2_S, b2, B, 0);
    conv1_k<<<512, 256, 0, stream>>>(x + 8 * 65536,   w1, b1, A);
    mfma_conv<CfgConv2><<<512, 256, 0, stream>>>(A, wsS + W2_S, b2, B, 8);

    // conv3: B -> h @ A  (2 rows/block: 16 n x 32 row-groups = 512 blocks)
    mfma_conv<CfgConv3><<<512, 256, 0, stream>>>(B, wsS + W3_S, b3, A, 0);

    // fused residual blocks (ping-pong A->B->A), 2 rows/block
    mfma_res<<<512, 256, 0, stream>>>(A, wsS + WR1_S, r1b1, wsS + WP1_S, r1b2, B);
    mfma_res<<<512, 256, 0, stream>>>(B, wsS + WR2_S, r2b1, wsS + WP2_S, r2b2, A);

    // 1x1 projection + vector quantization
    prevq_k<<<256, 256, 0, stream>>>(A, wpre, bpre, cb, out);
}

// Round 5
// 480.444 us; speedup vs baseline: 1.1225x; 1.1225x over previous
//
#include <hip/hip_runtime.h>
#include <math.h>

// ---------------------------------------------------------------------------
// ws layout:
//   shorts @0: repW2 393216, repW3 @393216 (442368), repR1 @835584 (110592),
//              repR2 @946176 (110592), repP1 @1056768 (12288), repP2 @1069056
//   floats:  B @4194304 : conv2 out / h' [16,128,64,64]
//            A @12582912: conv1 half-out [8,64,128,128] -> h [16,128,64,64]
// Flow: conv1->A, conv2 A->B (x2 halves); conv3 B->A; res1 A->B; res2 B->A;
//       prevq A->out.
//
// Round 5: conv2/conv3 = exact round-0 proven form (2-barrier, 38.4KB LDS,
//   acc[4][2], no spill). mfma_res restructured to 2 output rows per block:
//   wave (jrow, xhalf) owns 2 x-tiles x 2 nt of one row -> acc[2][2]=16 VGPR
//   (fits), B-loads per MFMA halved, staging 3 rows/output -> 2, barriers
//   halved. Stage-2 per-row sequential (a2[8], 32 VGPR). Register budget kept
//   small deliberately: R1/R4 lesson = spill (WRITE_SIZE >> 33MB) kills any
//   scheduling win. Per-output MFMA order unchanged -> bit-exact.
// ---------------------------------------------------------------------------

typedef short v8s __attribute__((ext_vector_type(8)));
typedef float v4f __attribute__((ext_vector_type(4)));

#define B_OFF 4194304
#define A_OFF 12582912
#define W2_S 0
#define W3_S 393216
#define WR1_S 835584
#define WR2_S 946176
#define WP1_S 1056768
#define WP2_S 1069056

// 3-limb bf16 truncation decomposition: x = h+m+l + O(2^-24 |x|)
__device__ inline void limb3(float v, unsigned short& h, unsigned short& m,
                             unsigned short& l) {
    unsigned ub = __float_as_uint(v);
    unsigned hb = ub & 0xffff0000u;
    float r1 = v - __uint_as_float(hb);
    unsigned mb = __float_as_uint(r1) & 0xffff0000u;
    float r2 = r1 - __uint_as_float(mb);
    unsigned lb = __float_as_uint(r2) & 0xffff0000u;
    h = (unsigned short)(hb >> 16);
    m = (unsigned short)(mb >> 16);
    l = (unsigned short)(lb >> 16);
}

// ----- conv configs ---------------------------------------------------------
struct CfgConv2 {   // 4x4 s2 p1 as stride-1 conv over 4 phase planes
    static constexpr int NC = 8, NT = 4, OC = 128, ICG = 64, IN_H = 128, IN_W = 128;
    static constexpr bool RELU_IN = false, RELU_OUT = true;
    __device__ static void tap(int c, int t, int& ry, int& rx) {
        int py = (c >> 2) & 1, px = (c >> 1) & 1;
        ry = (t >> 1) - py; rx = (t & 1) - px;
    }
    __device__ static void inaddr(int c, int oy, int r, int X,
                                  int& Yg, int& Xg, int& ic0) {
        int py = (c >> 2) & 1, px = (c >> 1) & 1;
        Yg = 2 * (oy + r - 1) + py; Xg = 2 * X + px; ic0 = (c & 1) * 32;
    }
    __device__ static int widx(int c, int t, int oc, int ic) {
        int py = (c >> 2) & 1, px = (c >> 1) & 1, half = c & 1;
        int dy = 2 * (t >> 1) + (1 - py), dx = 2 * (t & 1) + (1 - px);
        return ((oc * 64 + half * 32 + ic) * 4 + dy) * 4 + dx;
    }
};
struct CfgConv3 {   // 3x3 s1 p1, 128->128
    static constexpr int NC = 4, NT = 9, OC = 128, ICG = 128, IN_H = 64, IN_W = 64;
    static constexpr bool RELU_IN = false, RELU_OUT = false;
    __device__ static void tap(int c, int t, int& ry, int& rx) {
        ry = t / 3 - 1; rx = t % 3 - 1;
    }
    __device__ static void inaddr(int c, int oy, int r, int X,
                                  int& Yg, int& Xg, int& ic0) {
        Yg = oy + r - 1; Xg = X; ic0 = c * 32;
    }
    __device__ static int widx(int c, int t, int oc, int ic) {
        return ((oc * 128 + c * 32 + ic) * 3 + t / 3) * 3 + t % 3;
    }
};
struct CfgRes {     // 3x3 s1 p1, relu(in), 128->32
    static constexpr int NC = 4, NT = 9, OC = 32, ICG = 128, IN_H = 64, IN_W = 64;
    __device__ static int widx(int c, int t, int oc, int ic) {
        return ((oc * 128 + c * 32 + ic) * 3 + t / 3) * 3 + t % 3;
    }
};
struct Cfg1x1 {     // 1x1, 32->128
    static constexpr int NC = 1, NT = 1, OC = 128;
    __device__ static int widx(int c, int t, int oc, int ic) {
        return oc * 32 + ic;
    }
};

// ----- weight repack: fp32 -> per-lane B-fragment limb layout ---------------
// dst[(((ct*3+L)*NTILE + nt)<<9) + lane*8 + j], lane=q*16+o, oc=nt*16+o, ic=q*8+j
template <typename C>
__device__ inline void repack_one(const float* __restrict__ w,
                                  short* __restrict__ dst, int idx) {
    int s  = idx & 31;
    int oc = (idx >> 5) % C::OC;
    int ct = idx / (32 * C::OC);
    int c = ct / C::NT, t = ct % C::NT;
    float val = w[C::widx(c, t, oc, s)];
    unsigned short h, m, l;
    limb3(val, h, m, l);
    constexpr int NTILE = C::OC / 16;
    int nt = oc >> 4, o = oc & 15, q = s >> 3, j = s & 7;
    int fr = ((q * 16 + o) << 3) + j;
    dst[(((ct * 3 + 0) * NTILE + nt) << 9) + fr] = (short)h;
    dst[(((ct * 3 + 1) * NTILE + nt) << 9) + fr] = (short)m;
    dst[(((ct * 3 + 2) * NTILE + nt) << 9) + fr] = (short)l;
}

__global__ __launch_bounds__(256) void repack_all_k(
    const float* __restrict__ w2, const float* __restrict__ w3,
    const float* __restrict__ r1, const float* __restrict__ r2,
    const float* __restrict__ p1, const float* __restrict__ p2,
    short* __restrict__ base)
{
    int idx = blockIdx.x * 256 + threadIdx.x;
    if (idx < 131072) { repack_one<CfgConv2>(w2, base + W2_S, idx); return; }
    idx -= 131072;
    if (idx < 147456) { repack_one<CfgConv3>(w3, base + W3_S, idx); return; }
    idx -= 147456;
    if (idx < 36864)  { repack_one<CfgRes>(r1, base + WR1_S, idx); return; }
    idx -= 36864;
    if (idx < 36864)  { repack_one<CfgRes>(r2, base + WR2_S, idx); return; }
    idx -= 36864;
    if (idx < 4096)   { repack_one<Cfg1x1>(p1, base + WP1_S, idx); return; }
    idx -= 4096;
    if (idx < 4096)   { repack_one<Cfg1x1>(p2, base + WP2_S, idx); }
}

// ----- pipelined MFMA implicit-GEMM conv (WT_M=4, WT_N=2) — R0 proven -------
template <typename C>
__global__ __launch_bounds__(256, 3) void mfma_conv(
    const float* __restrict__ in, const short* __restrict__ repw,
    const float* __restrict__ bias, float* __restrict__ out, int n0)
{
    constexpr int APLANE = 3 * 66 * 32;        // shorts; dwords 3168
    constexpr int NTILE  = C::OC / 16;
    __shared__ __align__(16) short lA[3 * APLANE];

    int tid = threadIdx.x;
    int lane = tid & 63, wv = tid >> 6;
    int n_img = blockIdx.x >> 6, oy = blockIdx.x & 63;

    // zero halo cells (col 0 and 65, all rows, all limbs)
    for (int idx = tid; idx < 3 * 3 * 2 * 16; idx += 256) {
        int plane = idx / 96;
        int rem = idx % 96;
        int rr = rem / 32;
        int hc = (rem / 16) & 1;
        int d = idx & 15;
        ((unsigned*)lA)[plane * 3168 + (rr * 66 + hc * 65) * 16 + d] = 0;
    }

    v4f acc[4][2] = {};
    int nbase = wv * 2;
    int Xq = tid & 15, icp = tid >> 4, quad = lane >> 4;

    float pv[24];
    auto issue_loads = [&](int c) {
#pragma unroll
        for (int it = 0; it < 12; it++) {
            int r = it >> 2, xg = it & 3;
            int X = xg * 16 + Xq;
            int Yg, Xg, ic0;
            C::inaddr(c, oy, r, X, Yg, Xg, ic0);
            float v0 = 0.f, v1 = 0.f;
            if (Yg >= 0 && Yg < C::IN_H) {
                int g = ((n_img * C::ICG + ic0 + 2 * icp) * C::IN_H + Yg) * C::IN_W + Xg;
                v0 = in[g];
                v1 = in[g + C::IN_H * C::IN_W];
            }
            pv[2 * it] = v0; pv[2 * it + 1] = v1;
        }
    };
    auto load_bf = [&](int c, int t, v8s (&dst)[2][3]) {
#pragma unroll
        for (int nt = 0; nt < 2; nt++)
#pragma unroll
            for (int L = 0; L < 3; L++)
                dst[nt][L] = *(const v8s*)(repw +
                    ((((c * C::NT + t) * 3 + L) * NTILE + (nbase + nt)) << 9) +
                    (lane << 3));
    };

    issue_loads(0);

    for (int c = 0; c < C::NC; c++) {
        __syncthreads();   // prev chunk's readers done before lA overwrite
        // ---- consume pv -> lA limb planes ----
#pragma unroll
        for (int it = 0; it < 12; it++) {
            int r = it >> 2, xg = it & 3;
            int X = xg * 16 + Xq;
            float v0 = pv[2 * it], v1 = pv[2 * it + 1];
            if constexpr (C::RELU_IN) { v0 = fmaxf(v0, 0.f); v1 = fmaxf(v1, 0.f); }
            unsigned short h0, m0, l0, h1, m1, l1;
            limb3(v0, h0, m0, l0);
            limb3(v1, h1, m1, l1);
            int cell = r * 66 + X + 1;
            int f = (cell + (cell >> 2)) & 3;
            int phys = (icp & 3) + 4 * (((icp >> 2) + f) & 3);
            unsigned* pa = (unsigned*)lA + cell * 16 + phys;
            pa[0]        = (unsigned)h0 | ((unsigned)h1 << 16);
            pa[3168]     = (unsigned)m0 | ((unsigned)m1 << 16);
            pa[2 * 3168] = (unsigned)l0 | ((unsigned)l1 << 16);
        }
        __syncthreads();   // lA staged
        if (c + 1 < C::NC) issue_loads(c + 1);   // prefetch next chunk

        v8s bf[2][2][3];
        load_bf(c, 0, bf[0]);
#pragma unroll
        for (int t = 0; t < C::NT; t++) {
            constexpr int NTT = C::NT;
            if (t + 1 < NTT) load_bf(c, t + 1, bf[(t + 1) & 1]);
            int ry, rx;
            C::tap(c, t, ry, rx);
#pragma unroll
            for (int mt = 0; mt < 4; mt++) {
                int x = mt * 16 + (lane & 15);
                int cell = (ry + 1) * 66 + (x + rx + 1);
                int f = (cell + (cell >> 2)) & 3;
                int aa = cell * 32 + (((quad + f) & 3) << 3);
                v8s ah = *(const v8s*)&lA[aa];
                v8s am = *(const v8s*)&lA[APLANE + aa];
                v8s al = *(const v8s*)&lA[2 * APLANE + aa];
#pragma unroll
                for (int nt = 0; nt < 2; nt++) {
                    v4f a0 = acc[mt][nt];
                    a0 = __builtin_amdgcn_mfma_f32_16x16x32_bf16(ah, bf[t & 1][nt][0], a0, 0, 0, 0);
                    a0 = __builtin_amdgcn_mfma_f32_16x16x32_bf16(ah, bf[t & 1][nt][1], a0, 0, 0, 0);
                    a0 = __builtin_amdgcn_mfma_f32_16x16x32_bf16(am, bf[t & 1][nt][0], a0, 0, 0, 0);
                    a0 = __builtin_amdgcn_mfma_f32_16x16x32_bf16(am, bf[t & 1][nt][1], a0, 0, 0, 0);
                    a0 = __builtin_amdgcn_mfma_f32_16x16x32_bf16(ah, bf[t & 1][nt][2], a0, 0, 0, 0);
                    a0 = __builtin_amdgcn_mfma_f32_16x16x32_bf16(al, bf[t & 1][nt][0], a0, 0, 0, 0);
                    acc[mt][nt] = a0;
                }
            }
        }
    }
    // ---- epilogue: C/D layout col=lane&15 (oc), row=quad*4+reg (x) ----
#pragma unroll
    for (int mt = 0; mt < 4; mt++) {
        int x0 = mt * 16 + quad * 4;
#pragma unroll
        for (int nt = 0; nt < 2; nt++) {
            int oc = (nbase + nt) * 16 + (lane & 15);
            float bv = bias[oc];
            float v0 = acc[mt][nt][0] + bv;
            float v1 = acc[mt][nt][1] + bv;
            float v2 = acc[mt][nt][2] + bv;
            float v3 = acc[mt][nt][3] + bv;
            if constexpr (C::RELU_OUT) {
                v0 = fmaxf(v0, 0.f); v1 = fmaxf(v1, 0.f);
                v2 = fmaxf(v2, 0.f); v3 = fmaxf(v3, 0.f);
            }
            float4 o = make_float4(v0, v1, v2, v3);
            *(float4*)&out[(((n0 + n_img) * C::OC + oc) * 64 + oy) * 64 + x0] = o;
        }
    }
}

// ----- fused residual block, 2 output rows per block ------------------------
// t = conv3x3(relu(h)) + b1 (128->32);  out = h + conv1x1(relu(t)) + b2
// block = (n, row-pair oy0). Stage 1: 4-row input window; wave (jrow, xh)
// owns row jrow, x-tiles {2xh,2xh+1}, all 32 oc (2 nt) -> acc[2][2] (16 VGPR).
// Per tap: 24 MFMA / (6 B-loads + 6 A-reads); B-per-MFMA half of the old
// 1-row form. Stage 2: per-row sequential GEMM-2 (a2[8], 32 VGPR).
__global__ __launch_bounds__(256) void mfma_res(
    const float* __restrict__ in, const short* __restrict__ repw,
    const float* __restrict__ b1, const short* __restrict__ repp,
    const float* __restrict__ b2, float* __restrict__ out)
{
    constexpr int PLANE_D = 4 * 66 * 16;   // 4224 dwords per limb plane
    constexpr int PLANE_S = 2 * PLANE_D;   // 8448 shorts
    __shared__ __align__(16) short lA[3 * PLANE_S];   // 50688 B

    int tid = threadIdx.x;
    int lane = tid & 63, wv = tid >> 6;
    int n_img = blockIdx.x >> 5;
    int oy0 = (blockIdx.x & 31) << 1;
    int jrow = wv >> 1, xh = wv & 1;

    // zero halo cells (col 0 and 65, 4 window rows, all limbs)
    for (int idx = tid; idx < 3 * 4 * 2 * 16; idx += 256) {
        int plane = idx / 128;
        int rem = idx % 128;
        int rr = rem / 32;
        int hc = (rem >> 4) & 1;
        int d = idx & 15;
        ((unsigned*)lA)[plane * PLANE_D + (rr * 66 + hc * 65) * 16 + d] = 0;
    }

    v4f acc[2][2] = {};     // [mti][nt]
    int Xq = tid & 15, icp = tid >> 4, quad = lane >> 4;

    float pv[32];
    auto issue_loads = [&](int c) {
#pragma unroll
        for (int it = 0; it < 16; it++) {
            int r = it >> 2, xg = it & 3;
            int X = xg * 16 + Xq;
            int Yg = oy0 + r - 1;
            float v0 = 0.f, v1 = 0.f;
            if (Yg >= 0 && Yg < 64) {
                int g = ((n_img * 128 + c * 32 + 2 * icp) * 64 + Yg) * 64 + X;
                v0 = in[g];
                v1 = in[g + 4096];
            }
            pv[2 * it] = v0; pv[2 * it + 1] = v1;
        }
    };

    issue_loads(0);

    for (int c = 0; c < 4; c++) {
        __syncthreads();
#pragma unroll
        for (int it = 0; it < 16; it++) {
            int r = it >> 2, xg = it & 3;
            int X = xg * 16 + Xq;
            float v0 = fmaxf(pv[2 * it], 0.f);       // relu(h)
            float v1 = fmaxf(pv[2 * it + 1], 0.f);
            unsigned short h0, m0, l0, h1, m1, l1;
            limb3(v0, h0, m0, l0);
            limb3(v1, h1, m1, l1);
            int cell = r * 66 + X + 1;
            int f = (cell + (cell >> 2)) & 3;
            int phys = (icp & 3) + 4 * (((icp >> 2) + f) & 3);
            unsigned* pa = (unsigned*)lA + cell * 16 + phys;
            pa[0]           = (unsigned)h0 | ((unsigned)h1 << 16);
            pa[PLANE_D]     = (unsigned)m0 | ((unsigned)m1 << 16);
            pa[2 * PLANE_D] = (unsigned)l0 | ((unsigned)l1 << 16);
        }
        __syncthreads();
        if (c + 1 < 4) issue_loads(c + 1);

        v8s bf[2][2][3];
        auto load_bf = [&](int t, v8s (&dst)[2][3]) {
#pragma unroll
            for (int nt = 0; nt < 2; nt++)
#pragma unroll
                for (int L = 0; L < 3; L++)
                    dst[nt][L] = *(const v8s*)(repw +
                        ((((c * 9 + t) * 3 + L) * 2 + nt) << 9) + (lane << 3));
        };
        load_bf(0, bf[0]);
#pragma unroll
        for (int t = 0; t < 9; t++) {
            if (t + 1 < 9) load_bf(t + 1, bf[(t + 1) & 1]);
            int ry = t / 3 - 1, rx = t % 3 - 1;
#pragma unroll
            for (int mti = 0; mti < 2; mti++) {
                int x = (xh * 2 + mti) * 16 + (lane & 15);
                int cell = (jrow + ry + 1) * 66 + (x + rx + 1);
                int f = (cell + (cell >> 2)) & 3;
                int aa = cell * 32 + (((quad + f) & 3) << 3);
                v8s ah = *(const v8s*)&lA[aa];
                v8s am = *(const v8s*)&lA[PLANE_S + aa];
                v8s al = *(const v8s*)&lA[2 * PLANE_S + aa];
#pragma unroll
                for (int nt = 0; nt < 2; nt++) {
                    v4f a0 = acc[mti][nt];
                    a0 = __builtin_amdgcn_mfma_f32_16x16x32_bf16(ah, bf[t & 1][nt][0], a0, 0, 0, 0);
                    a0 = __builtin_amdgcn_mfma_f32_16x16x32_bf16(ah, bf[t & 1][nt][1], a0, 0, 0, 0);
                    a0 = __builtin_amdgcn_mfma_f32_16x16x32_bf16(am, bf[t & 1][nt][0], a0, 0, 0, 0);
                    a0 = __builtin_amdgcn_mfma_f32_16x16x32_bf16(am, bf[t & 1][nt][1], a0, 0, 0, 0);
                    a0 = __builtin_amdgcn_mfma_f32_16x16x32_bf16(ah, bf[t & 1][nt][2], a0, 0, 0, 0);
                    a0 = __builtin_amdgcn_mfma_f32_16x16x32_bf16(al, bf[t & 1][nt][0], a0, 0, 0, 0);
                    acc[mti][nt] = a0;
                }
            }
        }
    }

    // ===== stage 2: relu(t+b1) limbs -> LDS (A-frag layout, cell=x) =====
    // row j region at lA + j*6144 shorts (planes +0, +2048, +4096).
    __syncthreads();   // all lA tap-readers done; reuse front of lA
#pragma unroll
    for (int mti = 0; mti < 2; mti++) {
#pragma unroll
        for (int nt = 0; nt < 2; nt++) {
            int ic = nt * 16 + (lane & 15);     // t-channel = GEMM-2 k index
            int icp2 = ic >> 1, hilo = ic & 1;
            float bv = b1[ic];
#pragma unroll
            for (int r = 0; r < 4; r++) {
                int x = (xh * 2 + mti) * 16 + quad * 4 + r;
                float v = fmaxf(acc[mti][nt][r] + bv, 0.f);
                unsigned short h, m, l;
                limb3(v, h, m, l);
                int f = (x + (x >> 2)) & 3;
                int phys = (icp2 & 3) + 4 * (((icp2 >> 2) + f) & 3);
                int sa = x * 32 + phys * 2 + hilo;
                lA[jrow * 6144 + sa]        = (short)h;
                lA[jrow * 6144 + 2048 + sa] = (short)m;
                lA[jrow * 6144 + 4096 + sa] = (short)l;
            }
        }
    }
    __syncthreads();

    // GEMM-2 per row: M=64 (x, mt=wv), N=128 (oc2, nt=0..7), K=32
#pragma unroll
    for (int j = 0; j < 2; j++) {
        v4f a2[8] = {};
        int x = wv * 16 + (lane & 15);
        int f = (x + (x >> 2)) & 3;
        int aa = x * 32 + (((quad + f) & 3) << 3);
        v8s ah = *(const v8s*)&lA[j * 6144 + aa];
        v8s am = *(const v8s*)&lA[j * 6144 + 2048 + aa];
        v8s al = *(const v8s*)&lA[j * 6144 + 4096 + aa];
#pragma unroll
        for (int nt = 0; nt < 8; nt++) {
            v8s bh = *(const v8s*)(repp + ((0 * 8 + nt) << 9) + (lane << 3));
            v8s bm = *(const v8s*)(repp + ((1 * 8 + nt) << 9) + (lane << 3));
            v8s bl = *(const v8s*)(repp + ((2 * 8 + nt) << 9) + (lane << 3));
            v4f a0 = a2[nt];
            a0 = __builtin_amdgcn_mfma_f32_16x16x32_bf16(ah, bh, a0, 0, 0, 0);
            a0 = __builtin_amdgcn_mfma_f32_16x16x32_bf16(ah, bm, a0, 0, 0, 0);
            a0 = __builtin_amdgcn_mfma_f32_16x16x32_bf16(am, bh, a0, 0, 0, 0);
            a0 = __builtin_amdgcn_mfma_f32_16x16x32_bf16(am, bm, a0, 0, 0, 0);
            a0 = __builtin_amdgcn_mfma_f32_16x16x32_bf16(ah, bl, a0, 0, 0, 0);
            a0 = __builtin_amdgcn_mfma_f32_16x16x32_bf16(al, bh, a0, 0, 0, 0);
            a2[nt] = a0;
        }
        // epilogue row j: out = h + t2 + b2
#pragma unroll
        for (int nt = 0; nt < 8; nt++) {
            int oc = nt * 16 + (lane & 15);
            int x0 = wv * 16 + quad * 4;
            int off = ((n_img * 128 + oc) * 64 + (oy0 + j)) * 64 + x0;
            float4 hv = *(const float4*)&in[off];
            float bv = b2[oc];
            float4 o = make_float4(hv.x + a2[nt][0] + bv, hv.y + a2[nt][1] + bv,
                                   hv.z + a2[nt][2] + bv, hv.w + a2[nt][3] + bv);
            *(float4*)&out[off] = o;
        }
    }
}

// ----- conv1: [8,1,256,256] -> [8,64,128,128], 4x4 s2 p1, relu (fp32) -------
__global__ __launch_bounds__(256) void conv1_k(
    const float* __restrict__ x, const float* __restrict__ w,
    const float* __restrict__ b, float* __restrict__ out)
{
    int tid = blockIdx.x * 256 + threadIdx.x;     // 131072
    int n   = tid >> 14;
    int rem = tid & 16383;
    int oy  = rem >> 7;
    int ox  = rem & 127;
    int iy0 = oy * 2 - 1, ix0 = ox * 2 - 1;
    const float* xb = x + n * 65536;
    float v[16];
#pragma unroll
    for (int ky = 0; ky < 4; ky++) {
#pragma unroll
        for (int kx = 0; kx < 4; kx++) {
            int iy = iy0 + ky, ix = ix0 + kx;
            bool ok = (iy >= 0) & (iy < 256) & (ix >= 0) & (ix < 256);
            v[ky * 4 + kx] = ok ? xb[iy * 256 + ix] : 0.f;
        }
    }
    int obase = (n * 64) * 16384 + (oy << 7) + ox;
    for (int oc = 0; oc < 64; oc++) {
        float acc = b[oc];
        const float* wp = w + oc * 16;
#pragma unroll
        for (int k = 0; k < 16; k++) acc = fmaf(v[k], wp[k], acc);
        out[obase + oc * 16384] = fmaxf(acc, 0.f);
    }
}

// ----- fused 1x1 projection + cosine VQ (fp32, proven) ----------------------
__global__ __launch_bounds__(256) void prevq_k(
    const float* __restrict__ h, const float* __restrict__ wpre,
    const float* __restrict__ bpre, const float* __restrict__ cb,
    float* __restrict__ out)
{
    __shared__ float4 en[2048];
    for (int i = threadIdx.x; i < 2048; i += 256) {
        float c0 = cb[i * 4 + 0], c1 = cb[i * 4 + 1];
        float c2 = cb[i * 4 + 2], c3 = cb[i * 4 + 3];
        float nrm = sqrtf(c0 * c0 + c1 * c1 + c2 * c2 + c3 * c3) + 1e-12f;
        en[i] = make_float4(c0 / nrm, c1 / nrm, c2 / nrm, c3 / nrm);
    }
    __syncthreads();

    int tid = blockIdx.x * 256 + threadIdx.x;     // 65536
    int n   = tid >> 12;
    int pos = tid & 4095;
    const float* hb = h + n * 128 * 4096 + pos;
    float z0 = bpre[0], z1 = bpre[1], z2 = bpre[2], z3 = bpre[3];
    for (int ic = 0; ic < 128; ic++) {
        float v = fmaxf(hb[ic * 4096], 0.f);
        z0 = fmaf(v, wpre[ic],       z0);
        z1 = fmaf(v, wpre[128 + ic], z1);
        z2 = fmaf(v, wpre[256 + ic], z2);
        z3 = fmaf(v, wpre[384 + ic], z3);
    }
    // argmax of cosine sim is invariant to positive scaling of z
    float best = -1e30f;
    int   bidx = 0;
    for (int k = 0; k < 2048; k++) {
        float4 e = en[k];
        float s = z0 * e.x + z1 * e.y + z2 * e.z + z3 * e.w;
        if (s > best) { best = s; bidx = k; }     // strict > = first max
    }
    const float* q = cb + bidx * 4;
    out[(n * 4 + 0) * 4096 + pos] = q[0];
    out[(n * 4 + 1) * 4096 + pos] = q[1];
    out[(n * 4 + 2) * 4096 + pos] = q[2];
    out[(n * 4 + 3) * 4096 + pos] = q[3];
}

extern "C" void kernel_launch(void* const* d_in, const int* in_sizes, int n_in,
                              void* d_out, int out_size, void* d_ws, size_t ws_size,
                              hipStream_t stream)
{
    const float* x    = (const float*)d_in[0];
    const float* w1   = (const float*)d_in[1];
    const float* b1   = (const float*)d_in[2];
    const float* w2   = (const float*)d_in[3];
    const float* b2   = (const float*)d_in[4];
    const float* w3   = (const float*)d_in[5];
    const float* b3   = (const float*)d_in[6];
    const float* r1w1 = (const float*)d_in[7];
    const float* r1b1 = (const float*)d_in[8];
    const float* r1w2 = (const float*)d_in[9];
    const float* r1b2 = (const float*)d_in[10];
    const float* r2w1 = (const float*)d_in[11];
    const float* r2b1 = (const float*)d_in[12];
    const float* r2w2 = (const float*)d_in[13];
    const float* r2b2 = (const float*)d_in[14];
    const float* wpre = (const float*)d_in[15];
    const float* bpre = (const float*)d_in[16];
    const float* cb   = (const float*)d_in[17];
    float* out = (float*)d_out;

    float* ws   = (float*)d_ws;
    short* wsS  = (short*)d_ws;
    float* B = ws + B_OFF;
    float* A = ws + A_OFF;

    // one merged repack for all 6 weight tensors
    repack_all_k<<<1408, 256, 0, stream>>>(w2, w3, r1w1, r2w1, r1w2, r2w2, wsS);

    // front end, batch split in halves ping-ponging through A
    conv1_k<<<512, 256, 0, stream>>>(x,               w1, b1, A);
    mfma_conv<CfgConv2><<<512, 256, 0, stream>>>(A, wsS + W2_S, b2, B, 0);
    conv1_k<<<512, 256, 0, stream>>>(x + 8 * 65536,   w1, b1, A);
    mfma_conv<CfgConv2><<<512, 256, 0, stream>>>(A, wsS + W2_S, b2, B, 8);

    // conv3: B -> h @ A
    mfma_conv<CfgConv3><<<1024, 256, 0, stream>>>(B, wsS + W3_S, b3, A, 0);

    // fused residual blocks (ping-pong A->B->A), 2 rows/block
    mfma_res<<<512, 256, 0, stream>>>(A, wsS + WR1_S, r1b1, wsS + WP1_S, r1b2, B);
    mfma_res<<<512, 256, 0, stream>>>(B, wsS + WR2_S, r2b1, wsS + WP2_S, r2b2, A);

    // 1x1 projection + vector quantization
    prevq_k<<<256, 256, 0, stream>>>(A, wpre, bpre, cb, out);
}

// Round 6
// 462.335 us; speedup vs baseline: 1.1665x; 1.0392x over previous
//
#include <hip/hip_runtime.h>
#include <math.h>

// ---------------------------------------------------------------------------
// ws layout:
//   shorts @0: repW2 393216, repW3 @393216 (442368), repR1 @835584 (110592),
//              repR2 @946176 (110592), repP1 @1056768 (12288), repP2 @1069056
//   floats:  B @4194304 : conv2 out / h' [16,...]
//            A @12582912: conv1 half-out [8,...] -> h [16,...]
//
// Round 6: ACTIVATION LAYOUT CHANGE (pair-plane row-major). R0-R5 counters
//   show every MFMA kernel pinned at ~1 TB/s HBM with dur ~= hbm_bytes/1TB/s
//   (conv3: 88MB ~ 90us measured) -- far above compute floors. Cause: NCHW
//   puts a wave's staging loads at 64B per 16KB-strided channel plane ->
//   near-random 64B DRAM access. New layout for ALL intermediates:
//     64x64 tensors:  addr = ((n*64+y)*64 + c/2)*128 + (c&1)*64 + x
//     128x128 tensor: addr = ((n*128+y)*32 + c/2)*256 + (c&1)*128 + x
//   Staging reads become dense ~8KB row spans; epilogue float4 stores stay
//   contiguous. Values/limb3/LDS/MFMA/fma order all unchanged -> bit-exact.
// ---------------------------------------------------------------------------

typedef short v8s __attribute__((ext_vector_type(8)));
typedef float v4f __attribute__((ext_vector_type(4)));

#define B_OFF 4194304
#define A_OFF 12582912
#define W2_S 0
#define W3_S 393216
#define WR1_S 835584
#define WR2_S 946176
#define WP1_S 1056768
#define WP2_S 1069056

// 3-limb bf16 truncation decomposition: x = h+m+l + O(2^-24 |x|)
__device__ inline void limb3(float v, unsigned short& h, unsigned short& m,
                             unsigned short& l) {
    unsigned ub = __float_as_uint(v);
    unsigned hb = ub & 0xffff0000u;
    float r1 = v - __uint_as_float(hb);
    unsigned mb = __float_as_uint(r1) & 0xffff0000u;
    float r2 = r1 - __uint_as_float(mb);
    unsigned lb = __float_as_uint(r2) & 0xffff0000u;
    h = (unsigned short)(hb >> 16);
    m = (unsigned short)(mb >> 16);
    l = (unsigned short)(lb >> 16);
}

// ----- conv configs ---------------------------------------------------------
struct CfgConv2 {   // 4x4 s2 p1 as stride-1 conv over 4 phase planes
    static constexpr int NC = 8, NT = 4, OC = 128;
    static constexpr bool RELU_IN = false, RELU_OUT = true;
    __device__ static void tap(int c, int t, int& ry, int& rx) {
        int py = (c >> 2) & 1, px = (c >> 1) & 1;
        ry = (t >> 1) - py; rx = (t & 1) - px;
    }
    // pair-plane 128x128 input: ((n*128+Yg)*32 + pi)*256 + (parity)*128 + Xg
    __device__ static bool gaddr(int n, int oy, int r, int X, int icp, int c,
                                 int& g0, int& g1) {
        int py = (c >> 2) & 1, px = (c >> 1) & 1;
        int Yg = 2 * (oy + r - 1) + py;
        if (Yg < 0 || Yg >= 128) return false;
        int pi = (c & 1) * 16 + icp;
        g0 = ((n * 128 + Yg) * 32 + pi) * 256 + 2 * X + px;
        g1 = g0 + 128;
        return true;
    }
    __device__ static int widx(int c, int t, int oc, int ic) {
        int py = (c >> 2) & 1, px = (c >> 1) & 1, half = c & 1;
        int dy = 2 * (t >> 1) + (1 - py), dx = 2 * (t & 1) + (1 - px);
        return ((oc * 64 + half * 32 + ic) * 4 + dy) * 4 + dx;
    }
};
struct CfgConv3 {   // 3x3 s1 p1, 128->128
    static constexpr int NC = 4, NT = 9, OC = 128;
    static constexpr bool RELU_IN = false, RELU_OUT = false;
    __device__ static void tap(int c, int t, int& ry, int& rx) {
        ry = t / 3 - 1; rx = t % 3 - 1;
    }
    // pair-plane 64x64 input: ((n*64+Yg)*64 + pi)*128 + parity*64 + X
    __device__ static bool gaddr(int n, int oy, int r, int X, int icp, int c,
                                 int& g0, int& g1) {
        int Yg = oy + r - 1;
        if (Yg < 0 || Yg >= 64) return false;
        int pi = c * 16 + icp;
        g0 = ((n * 64 + Yg) * 64 + pi) * 128 + X;
        g1 = g0 + 64;
        return true;
    }
    __device__ static int widx(int c, int t, int oc, int ic) {
        return ((oc * 128 + c * 32 + ic) * 3 + t / 3) * 3 + t % 3;
    }
};
struct CfgRes {     // 3x3 s1 p1, relu(in), 128->32
    static constexpr int NC = 4, NT = 9, OC = 32;
    __device__ static int widx(int c, int t, int oc, int ic) {
        return ((oc * 128 + c * 32 + ic) * 3 + t / 3) * 3 + t % 3;
    }
};
struct Cfg1x1 {     // 1x1, 32->128
    static constexpr int NC = 1, NT = 1, OC = 128;
    __device__ static int widx(int c, int t, int oc, int ic) {
        return oc * 32 + ic;
    }
};

// ----- weight repack: fp32 -> per-lane B-fragment limb layout ---------------
template <typename C>
__device__ inline void repack_one(const float* __restrict__ w,
                                  short* __restrict__ dst, int idx) {
    int s  = idx & 31;
    int oc = (idx >> 5) % C::OC;
    int ct = idx / (32 * C::OC);
    int c = ct / C::NT, t = ct % C::NT;
    float val = w[C::widx(c, t, oc, s)];
    unsigned short h, m, l;
    limb3(val, h, m, l);
    constexpr int NTILE = C::OC / 16;
    int nt = oc >> 4, o = oc & 15, q = s >> 3, j = s & 7;
    int fr = ((q * 16 + o) << 3) + j;
    dst[(((ct * 3 + 0) * NTILE + nt) << 9) + fr] = (short)h;
    dst[(((ct * 3 + 1) * NTILE + nt) << 9) + fr] = (short)m;
    dst[(((ct * 3 + 2) * NTILE + nt) << 9) + fr] = (short)l;
}

__global__ __launch_bounds__(256) void repack_all_k(
    const float* __restrict__ w2, const float* __restrict__ w3,
    const float* __restrict__ r1, const float* __restrict__ r2,
    const float* __restrict__ p1, const float* __restrict__ p2,
    short* __restrict__ base)
{
    int idx = blockIdx.x * 256 + threadIdx.x;
    if (idx < 131072) { repack_one<CfgConv2>(w2, base + W2_S, idx); return; }
    idx -= 131072;
    if (idx < 147456) { repack_one<CfgConv3>(w3, base + W3_S, idx); return; }
    idx -= 147456;
    if (idx < 36864)  { repack_one<CfgRes>(r1, base + WR1_S, idx); return; }
    idx -= 36864;
    if (idx < 36864)  { repack_one<CfgRes>(r2, base + WR2_S, idx); return; }
    idx -= 36864;
    if (idx < 4096)   { repack_one<Cfg1x1>(p1, base + WP1_S, idx); return; }
    idx -= 4096;
    if (idx < 4096)   { repack_one<Cfg1x1>(p2, base + WP2_S, idx); }
}

// ----- pipelined MFMA implicit-GEMM conv (WT_M=4, WT_N=2) — R0 structure ----
template <typename C>
__global__ __launch_bounds__(256, 3) void mfma_conv(
    const float* __restrict__ in, const short* __restrict__ repw,
    const float* __restrict__ bias, float* __restrict__ out, int n0)
{
    constexpr int APLANE = 3 * 66 * 32;        // shorts; dwords 3168
    constexpr int NTILE  = C::OC / 16;
    __shared__ __align__(16) short lA[3 * APLANE];

    int tid = threadIdx.x;
    int lane = tid & 63, wv = tid >> 6;
    int n_img = blockIdx.x >> 6, oy = blockIdx.x & 63;

    // zero halo cells (col 0 and 65, all rows, all limbs)
    for (int idx = tid; idx < 3 * 3 * 2 * 16; idx += 256) {
        int plane = idx / 96;
        int rem = idx % 96;
        int rr = rem / 32;
        int hc = (rem / 16) & 1;
        int d = idx & 15;
        ((unsigned*)lA)[plane * 3168 + (rr * 66 + hc * 65) * 16 + d] = 0;
    }

    v4f acc[4][2] = {};
    int nbase = wv * 2;
    int Xq = tid & 15, icp = tid >> 4, quad = lane >> 4;

    float pv[24];
    auto issue_loads = [&](int c) {
#pragma unroll
        for (int it = 0; it < 12; it++) {
            int r = it >> 2, xg = it & 3;
            int X = xg * 16 + Xq;
            int g0, g1;
            float v0 = 0.f, v1 = 0.f;
            if (C::gaddr(n_img, oy, r, X, icp, c, g0, g1)) {
                v0 = in[g0];
                v1 = in[g1];
            }
            pv[2 * it] = v0; pv[2 * it + 1] = v1;
        }
    };
    auto load_bf = [&](int c, int t, v8s (&dst)[2][3]) {
#pragma unroll
        for (int nt = 0; nt < 2; nt++)
#pragma unroll
            for (int L = 0; L < 3; L++)
                dst[nt][L] = *(const v8s*)(repw +
                    ((((c * C::NT + t) * 3 + L) * NTILE + (nbase + nt)) << 9) +
                    (lane << 3));
    };

    issue_loads(0);

    for (int c = 0; c < C::NC; c++) {
        __syncthreads();   // prev chunk's readers done before lA overwrite
        // ---- consume pv -> lA limb planes ----
#pragma unroll
        for (int it = 0; it < 12; it++) {
            int r = it >> 2, xg = it & 3;
            int X = xg * 16 + Xq;
            float v0 = pv[2 * it], v1 = pv[2 * it + 1];
            if constexpr (C::RELU_IN) { v0 = fmaxf(v0, 0.f); v1 = fmaxf(v1, 0.f); }
            unsigned short h0, m0, l0, h1, m1, l1;
            limb3(v0, h0, m0, l0);
            limb3(v1, m1, m1, l1);   // placeholder overwritten below
            limb3(v1, h1, m1, l1);
            int cell = r * 66 + X + 1;
            int f = (cell + (cell >> 2)) & 3;
            int phys = (icp & 3) + 4 * (((icp >> 2) + f) & 3);
            unsigned* pa = (unsigned*)lA + cell * 16 + phys;
            pa[0]        = (unsigned)h0 | ((unsigned)h1 << 16);
            pa[3168]     = (unsigned)m0 | ((unsigned)m1 << 16);
            pa[2 * 3168] = (unsigned)l0 | ((unsigned)l1 << 16);
        }
        __syncthreads();   // lA staged
        if (c + 1 < C::NC) issue_loads(c + 1);   // prefetch next chunk

        v8s bf[2][2][3];
        load_bf(c, 0, bf[0]);
#pragma unroll
        for (int t = 0; t < C::NT; t++) {
            constexpr int NTT = C::NT;
            if (t + 1 < NTT) load_bf(c, t + 1, bf[(t + 1) & 1]);
            int ry, rx;
            C::tap(c, t, ry, rx);
#pragma unroll
            for (int mt = 0; mt < 4; mt++) {
                int x = mt * 16 + (lane & 15);
                int cell = (ry + 1) * 66 + (x + rx + 1);
                int f = (cell + (cell >> 2)) & 3;
                int aa = cell * 32 + (((quad + f) & 3) << 3);
                v8s ah = *(const v8s*)&lA[aa];
                v8s am = *(const v8s*)&lA[APLANE + aa];
                v8s al = *(const v8s*)&lA[2 * APLANE + aa];
#pragma unroll
                for (int nt = 0; nt < 2; nt++) {
                    v4f a0 = acc[mt][nt];
                    a0 = __builtin_amdgcn_mfma_f32_16x16x32_bf16(ah, bf[t & 1][nt][0], a0, 0, 0, 0);
                    a0 = __builtin_amdgcn_mfma_f32_16x16x32_bf16(ah, bf[t & 1][nt][1], a0, 0, 0, 0);
                    a0 = __builtin_amdgcn_mfma_f32_16x16x32_bf16(am, bf[t & 1][nt][0], a0, 0, 0, 0);
                    a0 = __builtin_amdgcn_mfma_f32_16x16x32_bf16(am, bf[t & 1][nt][1], a0, 0, 0, 0);
                    a0 = __builtin_amdgcn_mfma_f32_16x16x32_bf16(ah, bf[t & 1][nt][2], a0, 0, 0, 0);
                    a0 = __builtin_amdgcn_mfma_f32_16x16x32_bf16(al, bf[t & 1][nt][0], a0, 0, 0, 0);
                    acc[mt][nt] = a0;
                }
            }
        }
    }
    // ---- epilogue: pair-plane store, col=lane&15 (oc), row=quad*4+reg (x) --
#pragma unroll
    for (int mt = 0; mt < 4; mt++) {
        int x0 = mt * 16 + quad * 4;
#pragma unroll
        for (int nt = 0; nt < 2; nt++) {
            int oc = (nbase + nt) * 16 + (lane & 15);
            float bv = bias[oc];
            float v0 = acc[mt][nt][0] + bv;
            float v1 = acc[mt][nt][1] + bv;
            float v2 = acc[mt][nt][2] + bv;
            float v3 = acc[mt][nt][3] + bv;
            if constexpr (C::RELU_OUT) {
                v0 = fmaxf(v0, 0.f); v1 = fmaxf(v1, 0.f);
                v2 = fmaxf(v2, 0.f); v3 = fmaxf(v3, 0.f);
            }
            float4 o = make_float4(v0, v1, v2, v3);
            int off = (((n0 + n_img) * 64 + oy) * 64 + (oc >> 1)) * 128 +
                      (oc & 1) * 64 + x0;
            *(float4*)&out[off] = o;
        }
    }
}

// ----- fused residual block, 2 output rows per block (R5 structure) ---------
__global__ __launch_bounds__(256) void mfma_res(
    const float* __restrict__ in, const short* __restrict__ repw,
    const float* __restrict__ b1, const short* __restrict__ repp,
    const float* __restrict__ b2, float* __restrict__ out)
{
    constexpr int PLANE_D = 4 * 66 * 16;   // 4224 dwords per limb plane
    constexpr int PLANE_S = 2 * PLANE_D;   // 8448 shorts
    __shared__ __align__(16) short lA[3 * PLANE_S];   // 50688 B

    int tid = threadIdx.x;
    int lane = tid & 63, wv = tid >> 6;
    int n_img = blockIdx.x >> 5;
    int oy0 = (blockIdx.x & 31) << 1;
    int jrow = wv >> 1, xh = wv & 1;

    for (int idx = tid; idx < 3 * 4 * 2 * 16; idx += 256) {
        int plane = idx / 128;
        int rem = idx % 128;
        int rr = rem / 32;
        int hc = (rem >> 4) & 1;
        int d = idx & 15;
        ((unsigned*)lA)[plane * PLANE_D + (rr * 66 + hc * 65) * 16 + d] = 0;
    }

    v4f acc[2][2] = {};     // [mti][nt]
    int Xq = tid & 15, icp = tid >> 4, quad = lane >> 4;

    float pv[32];
    auto issue_loads = [&](int c) {
#pragma unroll
        for (int it = 0; it < 16; it++) {
            int r = it >> 2, xg = it & 3;
            int X = xg * 16 + Xq;
            int Yg = oy0 + r - 1;
            float v0 = 0.f, v1 = 0.f;
            if (Yg >= 0 && Yg < 64) {
                int g = ((n_img * 64 + Yg) * 64 + (c * 16 + icp)) * 128 + X;
                v0 = in[g];
                v1 = in[g + 64];
            }
            pv[2 * it] = v0; pv[2 * it + 1] = v1;
        }
    };

    issue_loads(0);

    for (int c = 0; c < 4; c++) {
        __syncthreads();
#pragma unroll
        for (int it = 0; it < 16; it++) {
            int r = it >> 2, xg = it & 3;
            int X = xg * 16 + Xq;
            float v0 = fmaxf(pv[2 * it], 0.f);       // relu(h)
            float v1 = fmaxf(pv[2 * it + 1], 0.f);
            unsigned short h0, m0, l0, h1, m1, l1;
            limb3(v0, h0, m0, l0);
            limb3(v1, h1, m1, l1);
            int cell = r * 66 + X + 1;
            int f = (cell + (cell >> 2)) & 3;
            int phys = (icp & 3) + 4 * (((icp >> 2) + f) & 3);
            unsigned* pa = (unsigned*)lA + cell * 16 + phys;
            pa[0]           = (unsigned)h0 | ((unsigned)h1 << 16);
            pa[PLANE_D]     = (unsigned)m0 | ((unsigned)m1 << 16);
            pa[2 * PLANE_D] = (unsigned)l0 | ((unsigned)l1 << 16);
        }
        __syncthreads();
        if (c + 1 < 4) issue_loads(c + 1);

        v8s bf[2][2][3];
        auto load_bf = [&](int t, v8s (&dst)[2][3]) {
#pragma unroll
            for (int nt = 0; nt < 2; nt++)
#pragma unroll
                for (int L = 0; L < 3; L++)
                    dst[nt][L] = *(const v8s*)(repw +
                        ((((c * 9 + t) * 3 + L) * 2 + nt) << 9) + (lane << 3));
        };
        load_bf(0, bf[0]);
#pragma unroll
        for (int t = 0; t < 9; t++) {
            if (t + 1 < 9) load_bf(t + 1, bf[(t + 1) & 1]);
            int ry = t / 3 - 1, rx = t % 3 - 1;
#pragma unroll
            for (int mti = 0; mti < 2; mti++) {
                int x = (xh * 2 + mti) * 16 + (lane & 15);
                int cell = (jrow + ry + 1) * 66 + (x + rx + 1);
                int f = (cell + (cell >> 2)) & 3;
                int aa = cell * 32 + (((quad + f) & 3) << 3);
                v8s ah = *(const v8s*)&lA[aa];
                v8s am = *(const v8s*)&lA[PLANE_S + aa];
                v8s al = *(const v8s*)&lA[2 * PLANE_S + aa];
#pragma unroll
                for (int nt = 0; nt < 2; nt++) {
                    v4f a0 = acc[mti][nt];
                    a0 = __builtin_amdgcn_mfma_f32_16x16x32_bf16(ah, bf[t & 1][nt][0], a0, 0, 0, 0);
                    a0 = __builtin_amdgcn_mfma_f32_16x16x32_bf16(ah, bf[t & 1][nt][1], a0, 0, 0, 0);
                    a0 = __builtin_amdgcn_mfma_f32_16x16x32_bf16(am, bf[t & 1][nt][0], a0, 0, 0, 0);
                    a0 = __builtin_amdgcn_mfma_f32_16x16x32_bf16(am, bf[t & 1][nt][1], a0, 0, 0, 0);
                    a0 = __builtin_amdgcn_mfma_f32_16x16x32_bf16(ah, bf[t & 1][nt][2], a0, 0, 0, 0);
                    a0 = __builtin_amdgcn_mfma_f32_16x16x32_bf16(al, bf[t & 1][nt][0], a0, 0, 0, 0);
                    acc[mti][nt] = a0;
                }
            }
        }
    }

    // ===== stage 2: relu(t+b1) limbs -> LDS (A-frag layout, cell=x) =====
    __syncthreads();   // all lA tap-readers done; reuse front of lA
#pragma unroll
    for (int mti = 0; mti < 2; mti++) {
#pragma unroll
        for (int nt = 0; nt < 2; nt++) {
            int ic = nt * 16 + (lane & 15);     // t-channel = GEMM-2 k index
            int icp2 = ic >> 1, hilo = ic & 1;
            float bv = b1[ic];
#pragma unroll
            for (int r = 0; r < 4; r++) {
                int x = (xh * 2 + mti) * 16 + quad * 4 + r;
                float v = fmaxf(acc[mti][nt][r] + bv, 0.f);
                unsigned short h, m, l;
                limb3(v, h, m, l);
                int f = (x + (x >> 2)) & 3;
                int phys = (icp2 & 3) + 4 * (((icp2 >> 2) + f) & 3);
                int sa = x * 32 + phys * 2 + hilo;
                lA[jrow * 6144 + sa]        = (short)h;
                lA[jrow * 6144 + 2048 + sa] = (short)m;
                lA[jrow * 6144 + 4096 + sa] = (short)l;
            }
        }
    }
    __syncthreads();

    // GEMM-2 per row: M=64 (x, mt=wv), N=128 (oc2, nt=0..7), K=32
#pragma unroll
    for (int j = 0; j < 2; j++) {
        v4f a2[8] = {};
        int x = wv * 16 + (lane & 15);
        int f = (x + (x >> 2)) & 3;
        int aa = x * 32 + (((quad + f) & 3) << 3);
        v8s ah = *(const v8s*)&lA[j * 6144 + aa];
        v8s am = *(const v8s*)&lA[j * 6144 + 2048 + aa];
        v8s al = *(const v8s*)&lA[j * 6144 + 4096 + aa];
#pragma unroll
        for (int nt = 0; nt < 8; nt++) {
            v8s bh = *(const v8s*)(repp + ((0 * 8 + nt) << 9) + (lane << 3));
            v8s bm = *(const v8s*)(repp + ((1 * 8 + nt) << 9) + (lane << 3));
            v8s bl = *(const v8s*)(repp + ((2 * 8 + nt) << 9) + (lane << 3));
            v4f a0 = a2[nt];
            a0 = __builtin_amdgcn_mfma_f32_16x16x32_bf16(ah, bh, a0, 0, 0, 0);
            a0 = __builtin_amdgcn_mfma_f32_16x16x32_bf16(ah, bm, a0, 0, 0, 0);
            a0 = __builtin_amdgcn_mfma_f32_16x16x32_bf16(am, bh, a0, 0, 0, 0);
            a0 = __builtin_amdgcn_mfma_f32_16x16x32_bf16(am, bm, a0, 0, 0, 0);
            a0 = __builtin_amdgcn_mfma_f32_16x16x32_bf16(ah, bl, a0, 0, 0, 0);
            a0 = __builtin_amdgcn_mfma_f32_16x16x32_bf16(al, bh, a0, 0, 0, 0);
            a2[nt] = a0;
        }
        // epilogue row j: out = h + t2 + b2   (pair-plane layout)
#pragma unroll
        for (int nt = 0; nt < 8; nt++) {
            int oc = nt * 16 + (lane & 15);
            int x0 = wv * 16 + quad * 4;
            int off = ((n_img * 64 + (oy0 + j)) * 64 + (oc >> 1)) * 128 +
                      (oc & 1) * 64 + x0;
            float4 hv = *(const float4*)&in[off];
            float bv = b2[oc];
            float4 o = make_float4(hv.x + a2[nt][0] + bv, hv.y + a2[nt][1] + bv,
                                   hv.z + a2[nt][2] + bv, hv.w + a2[nt][3] + bv);
            *(float4*)&out[off] = o;
        }
    }
}

// ----- conv1: [8,1,256,256] -> pair-plane [8][128][32][2][128], relu --------
__global__ __launch_bounds__(256) void conv1_k(
    const float* __restrict__ x, const float* __restrict__ w,
    const float* __restrict__ b, float* __restrict__ out)
{
    int tid = blockIdx.x * 256 + threadIdx.x;     // 131072
    int n   = tid >> 14;
    int rem = tid & 16383;
    int oy  = rem >> 7;
    int ox  = rem & 127;
    int iy0 = oy * 2 - 1, ix0 = ox * 2 - 1;
    const float* xb = x + n * 65536;
    float v[16];
#pragma unroll
    for (int ky = 0; ky < 4; ky++) {
#pragma unroll
        for (int kx = 0; kx < 4; kx++) {
            int iy = iy0 + ky, ix = ix0 + kx;
            bool ok = (iy >= 0) & (iy < 256) & (ix >= 0) & (ix < 256);
            v[ky * 4 + kx] = ok ? xb[iy * 256 + ix] : 0.f;
        }
    }
    int obase = (n * 128 + oy) * 8192 + ox;   // (n*128+oy)*32*256
    for (int oc = 0; oc < 64; oc++) {
        float acc = b[oc];
        const float* wp = w + oc * 16;
#pragma unroll
        for (int k = 0; k < 16; k++) acc = fmaf(v[k], wp[k], acc);
        out[obase + (oc >> 1) * 256 + (oc & 1) * 128] = fmaxf(acc, 0.f);
    }
}

// ----- fused 1x1 projection + cosine VQ (fp32, proven) ----------------------
__global__ __launch_bounds__(256) void prevq_k(
    const float* __restrict__ h, const float* __restrict__ wpre,
    const float* __restrict__ bpre, const float* __restrict__ cb,
    float* __restrict__ out)
{
    __shared__ float4 en[2048];
    for (int i = threadIdx.x; i < 2048; i += 256) {
        float c0 = cb[i * 4 + 0], c1 = cb[i * 4 + 1];
        float c2 = cb[i * 4 + 2], c3 = cb[i * 4 + 3];
        float nrm = sqrtf(c0 * c0 + c1 * c1 + c2 * c2 + c3 * c3) + 1e-12f;
        en[i] = make_float4(c0 / nrm, c1 / nrm, c2 / nrm, c3 / nrm);
    }
    __syncthreads();

    int tid = blockIdx.x * 256 + threadIdx.x;     // 65536
    int n   = tid >> 12;
    int pos = tid & 4095;
    int y = pos >> 6, xx = pos & 63;
    // pair-plane input: ((n*64+y)*64 + icp)*128 + parity*64 + xx
    const float* hb = h + ((n * 64 + y) * 64) * 128 + xx;
    float z0 = bpre[0], z1 = bpre[1], z2 = bpre[2], z3 = bpre[3];
    for (int icp = 0; icp < 64; icp++) {
        float v0 = fmaxf(hb[icp * 128], 0.f);          // ic = 2*icp
        int ic = 2 * icp;
        z0 = fmaf(v0, wpre[ic],       z0);
        z1 = fmaf(v0, wpre[128 + ic], z1);
        z2 = fmaf(v0, wpre[256 + ic], z2);
        z3 = fmaf(v0, wpre[384 + ic], z3);
        float v1 = fmaxf(hb[icp * 128 + 64], 0.f);     // ic = 2*icp+1
        z0 = fmaf(v1, wpre[ic + 1],       z0);
        z1 = fmaf(v1, wpre[128 + ic + 1], z1);
        z2 = fmaf(v1, wpre[256 + ic + 1], z2);
        z3 = fmaf(v1, wpre[384 + ic + 1], z3);
    }
    // argmax of cosine sim is invariant to positive scaling of z
    float best = -1e30f;
    int   bidx = 0;
    for (int k = 0; k < 2048; k++) {
        float4 e = en[k];
        float s = z0 * e.x + z1 * e.y + z2 * e.z + z3 * e.w;
        if (s > best) { best = s; bidx = k; }     // strict > = first max
    }
    const float* q = cb + bidx * 4;
    out[(n * 4 + 0) * 4096 + pos] = q[0];
    out[(n * 4 + 1) * 4096 + pos] = q[1];
    out[(n * 4 + 2) * 4096 + pos] = q[2];
    out[(n * 4 + 3) * 4096 + pos] = q[3];
}

extern "C" void kernel_launch(void* const* d_in, const int* in_sizes, int n_in,
                              void* d_out, int out_size, void* d_ws, size_t ws_size,
                              hipStream_t stream)
{
    const float* x    = (const float*)d_in[0];
    const float* w1   = (const float*)d_in[1];
    const float* b1   = (const float*)d_in[2];
    const float* w2   = (const float*)d_in[3];
    const float* b2   = (const float*)d_in[4];
    const float* w3   = (const float*)d_in[5];
    const float* b3   = (const float*)d_in[6];
    const float* r1w1 = (const float*)d_in[7];
    const float* r1b1 = (const float*)d_in[8];
    const float* r1w2 = (const float*)d_in[9];
    const float* r1b2 = (const float*)d_in[10];
    const float* r2w1 = (const float*)d_in[11];
    const float* r2b1 = (const float*)d_in[12];
    const float* r2w2 = (const float*)d_in[13];
    const float* r2b2 = (const float*)d_in[14];
    const float* wpre = (const float*)d_in[15];
    const float* bpre = (const float*)d_in[16];
    const float* cb   = (const float*)d_in[17];
    float* out = (float*)d_out;

    float* ws   = (float*)d_ws;
    short* wsS  = (short*)d_ws;
    float* B = ws + B_OFF;
    float* A = ws + A_OFF;

    // one merged repack for all 6 weight tensors
    repack_all_k<<<1408, 256, 0, stream>>>(w2, w3, r1w1, r2w1, r1w2, r2w2, wsS);

    // front end, batch split in halves ping-ponging through A
    conv1_k<<<512, 256, 0, stream>>>(x,               w1, b1, A);
    mfma_conv<CfgConv2><<<512, 256, 0, stream>>>(A, wsS + W2_S, b2, B, 0);
    conv1_k<<<512, 256, 0, stream>>>(x + 8 * 65536,   w1, b1, A);
    mfma_conv<CfgConv2><<<512, 256, 0, stream>>>(A, wsS + W2_S, b2, B, 8);

    // conv3: B -> h @ A
    mfma_conv<CfgConv3><<<1024, 256, 0, stream>>>(B, wsS + W3_S, b3, A, 0);

    // fused residual blocks (ping-pong A->B->A), 2 rows/block
    mfma_res<<<512, 256, 0, stream>>>(A, wsS + WR1_S, r1b1, wsS + WP1_S, r1b2, B);
    mfma_res<<<512, 256, 0, stream>>>(B, wsS + WR2_S, r2b1, wsS + WP2_S, r2b2, A);

    // 1x1 projection + vector quantization
    prevq_k<<<256, 256, 0, stream>>>(A, wpre, bpre, cb, out);
}

// Round 8
// 456.644 us; speedup vs baseline: 1.1810x; 1.0125x over previous
//
#include <hip/hip_runtime.h>
#include <math.h>

// ---------------------------------------------------------------------------
// ws layout:
//   shorts @0: repW2 393216, repW3 @393216 (442368), repR1 @835584 (110592),
//              repR2 @946176 (110592), repP1 @1056768 (12288), repP2 @1069056
//   floats:  B @4194304 : conv2 out / h' [16,...]  (64x64 pair-plane)
//            A @12582912: conv1 half-out [8,...] (phase-split) -> h [16,...]
//
// Round 8 == round 7 resubmit (infra failure, kernel re-audited):
//  1) conv1->conv2 interface: phase-split pair-plane layout
//       addr = (((n*4 + py*2 + px)*64 + y2)*32 + pi)*128 + parity*64 + x2
//     conv2 staging reads become unit-stride (R6 still had stride-2 reads
//     wasting half of each cacheline). Values bit-identical.
//  2) prevq: 4-way parallel argmax. Old: 1 thread/position scans 2048 codes
//     serially at 4 waves/CU (VALU-serial). New: 1024 blocks x 64 positions;
//     per-wave partial z (coalesced), LDS combine in fixed order, 4 threads
//     per position scan 512 codes each, shfl_xor (max s, tie min idx) reduce
//     == exact global first-max semantics.
// ---------------------------------------------------------------------------

typedef short v8s __attribute__((ext_vector_type(8)));
typedef float v4f __attribute__((ext_vector_type(4)));

#define B_OFF 4194304
#define A_OFF 12582912
#define W2_S 0
#define W3_S 393216
#define WR1_S 835584
#define WR2_S 946176
#define WP1_S 1056768
#define WP2_S 1069056

// 3-limb bf16 truncation decomposition: x = h+m+l + O(2^-24 |x|)
__device__ inline void limb3(float v, unsigned short& h, unsigned short& m,
                             unsigned short& l) {
    unsigned ub = __float_as_uint(v);
    unsigned hb = ub & 0xffff0000u;
    float r1 = v - __uint_as_float(hb);
    unsigned mb = __float_as_uint(r1) & 0xffff0000u;
    float r2 = r1 - __uint_as_float(mb);
    unsigned lb = __float_as_uint(r2) & 0xffff0000u;
    h = (unsigned short)(hb >> 16);
    m = (unsigned short)(mb >> 16);
    l = (unsigned short)(lb >> 16);
}

// ----- conv configs ---------------------------------------------------------
struct CfgConv2 {   // 4x4 s2 p1 as stride-1 conv over 4 phase planes
    static constexpr int NC = 8, NT = 4, OC = 128;
    static constexpr bool RELU_IN = false, RELU_OUT = true;
    __device__ static void tap(int c, int t, int& ry, int& rx) {
        int py = (c >> 2) & 1, px = (c >> 1) & 1;
        ry = (t >> 1) - py; rx = (t & 1) - px;
    }
    // phase-split pair-plane input (see header). Unit-stride in X.
    __device__ static bool gaddr(int n, int oy, int r, int X, int icp, int c,
                                 int& g0, int& g1) {
        int py = (c >> 2) & 1, px = (c >> 1) & 1;
        int y2 = oy + r - 1;
        if (y2 < 0 || y2 >= 64) return false;
        int pi = (c & 1) * 16 + icp;
        g0 = (((n * 4 + py * 2 + px) * 64 + y2) * 32 + pi) * 128 + X;
        g1 = g0 + 64;
        return true;
    }
    __device__ static int widx(int c, int t, int oc, int ic) {
        int py = (c >> 2) & 1, px = (c >> 1) & 1, half = c & 1;
        int dy = 2 * (t >> 1) + (1 - py), dx = 2 * (t & 1) + (1 - px);
        return ((oc * 64 + half * 32 + ic) * 4 + dy) * 4 + dx;
    }
};
struct CfgConv3 {   // 3x3 s1 p1, 128->128
    static constexpr int NC = 4, NT = 9, OC = 128;
    static constexpr bool RELU_IN = false, RELU_OUT = false;
    __device__ static void tap(int c, int t, int& ry, int& rx) {
        ry = t / 3 - 1; rx = t % 3 - 1;
    }
    // pair-plane 64x64 input: ((n*64+Yg)*64 + pi)*128 + parity*64 + X
    __device__ static bool gaddr(int n, int oy, int r, int X, int icp, int c,
                                 int& g0, int& g1) {
        int Yg = oy + r - 1;
        if (Yg < 0 || Yg >= 64) return false;
        int pi = c * 16 + icp;
        g0 = ((n * 64 + Yg) * 64 + pi) * 128 + X;
        g1 = g0 + 64;
        return true;
    }
    __device__ static int widx(int c, int t, int oc, int ic) {
        return ((oc * 128 + c * 32 + ic) * 3 + t / 3) * 3 + t % 3;
    }
};
struct CfgRes {     // 3x3 s1 p1, relu(in), 128->32
    static constexpr int NC = 4, NT = 9, OC = 32;
    __device__ static int widx(int c, int t, int oc, int ic) {
        return ((oc * 128 + c * 32 + ic) * 3 + t / 3) * 3 + t % 3;
    }
};
struct Cfg1x1 {     // 1x1, 32->128
    static constexpr int NC = 1, NT = 1, OC = 128;
    __device__ static int widx(int c, int t, int oc, int ic) {
        return oc * 32 + ic;
    }
};

// ----- weight repack: fp32 -> per-lane B-fragment limb layout ---------------
template <typename C>
__device__ inline void repack_one(const float* __restrict__ w,
                                  short* __restrict__ dst, int idx) {
    int s  = idx & 31;
    int oc = (idx >> 5) % C::OC;
    int ct = idx / (32 * C::OC);
    int c = ct / C::NT, t = ct % C::NT;
    float val = w[C::widx(c, t, oc, s)];
    unsigned short h, m, l;
    limb3(val, h, m, l);
    constexpr int NTILE = C::OC / 16;
    int nt = oc >> 4, o = oc & 15, q = s >> 3, j = s & 7;
    int fr = ((q * 16 + o) << 3) + j;
    dst[(((ct * 3 + 0) * NTILE + nt) << 9) + fr] = (short)h;
    dst[(((ct * 3 + 1) * NTILE + nt) << 9) + fr] = (short)m;
    dst[(((ct * 3 + 2) * NTILE + nt) << 9) + fr] = (short)l;
}

__global__ __launch_bounds__(256) void repack_all_k(
    const float* __restrict__ w2, const float* __restrict__ w3,
    const float* __restrict__ r1, const float* __restrict__ r2,
    const float* __restrict__ p1, const float* __restrict__ p2,
    short* __restrict__ base)
{
    int idx = blockIdx.x * 256 + threadIdx.x;
    if (idx < 131072) { repack_one<CfgConv2>(w2, base + W2_S, idx); return; }
    idx -= 131072;
    if (idx < 147456) { repack_one<CfgConv3>(w3, base + W3_S, idx); return; }
    idx -= 147456;
    if (idx < 36864)  { repack_one<CfgRes>(r1, base + WR1_S, idx); return; }
    idx -= 36864;
    if (idx < 36864)  { repack_one<CfgRes>(r2, base + WR2_S, idx); return; }
    idx -= 36864;
    if (idx < 4096)   { repack_one<Cfg1x1>(p1, base + WP1_S, idx); return; }
    idx -= 4096;
    if (idx < 4096)   { repack_one<Cfg1x1>(p2, base + WP2_S, idx); }
}

// ----- pipelined MFMA implicit-GEMM conv (WT_M=4, WT_N=2) — R0 structure ----
template <typename C>
__global__ __launch_bounds__(256, 3) void mfma_conv(
    const float* __restrict__ in, const short* __restrict__ repw,
    const float* __restrict__ bias, float* __restrict__ out, int n0)
{
    constexpr int APLANE = 3 * 66 * 32;        // shorts; dwords 3168
    constexpr int NTILE  = C::OC / 16;
    __shared__ __align__(16) short lA[3 * APLANE];

    int tid = threadIdx.x;
    int lane = tid & 63, wv = tid >> 6;
    int n_img = blockIdx.x >> 6, oy = blockIdx.x & 63;

    // zero halo cells (col 0 and 65, all rows, all limbs)
    for (int idx = tid; idx < 3 * 3 * 2 * 16; idx += 256) {
        int plane = idx / 96;
        int rem = idx % 96;
        int rr = rem / 32;
        int hc = (rem / 16) & 1;
        int d = idx & 15;
        ((unsigned*)lA)[plane * 3168 + (rr * 66 + hc * 65) * 16 + d] = 0;
    }

    v4f acc[4][2] = {};
    int nbase = wv * 2;
    int Xq = tid & 15, icp = tid >> 4, quad = lane >> 4;

    float pv[24];
    auto issue_loads = [&](int c) {
#pragma unroll
        for (int it = 0; it < 12; it++) {
            int r = it >> 2, xg = it & 3;
            int X = xg * 16 + Xq;
            int g0, g1;
            float v0 = 0.f, v1 = 0.f;
            if (C::gaddr(n_img, oy, r, X, icp, c, g0, g1)) {
                v0 = in[g0];
                v1 = in[g1];
            }
            pv[2 * it] = v0; pv[2 * it + 1] = v1;
        }
    };
    auto load_bf = [&](int c, int t, v8s (&dst)[2][3]) {
#pragma unroll
        for (int nt = 0; nt < 2; nt++)
#pragma unroll
            for (int L = 0; L < 3; L++)
                dst[nt][L] = *(const v8s*)(repw +
                    ((((c * C::NT + t) * 3 + L) * NTILE + (nbase + nt)) << 9) +
                    (lane << 3));
    };

    issue_loads(0);

    for (int c = 0; c < C::NC; c++) {
        __syncthreads();   // prev chunk's readers done before lA overwrite
        // ---- consume pv -> lA limb planes ----
#pragma unroll
        for (int it = 0; it < 12; it++) {
            int r = it >> 2, xg = it & 3;
            int X = xg * 16 + Xq;
            float v0 = pv[2 * it], v1 = pv[2 * it + 1];
            if constexpr (C::RELU_IN) { v0 = fmaxf(v0, 0.f); v1 = fmaxf(v1, 0.f); }
            unsigned short h0, m0, l0, h1, m1, l1;
            limb3(v0, h0, m0, l0);
            limb3(v1, h1, m1, l1);
            int cell = r * 66 + X + 1;
            int f = (cell + (cell >> 2)) & 3;
            int phys = (icp & 3) + 4 * (((icp >> 2) + f) & 3);
            unsigned* pa = (unsigned*)lA + cell * 16 + phys;
            pa[0]        = (unsigned)h0 | ((unsigned)h1 << 16);
            pa[3168]     = (unsigned)m0 | ((unsigned)m1 << 16);
            pa[2 * 3168] = (unsigned)l0 | ((unsigned)l1 << 16);
        }
        __syncthreads();   // lA staged
        if (c + 1 < C::NC) issue_loads(c + 1);   // prefetch next chunk

        v8s bf[2][2][3];
        load_bf(c, 0, bf[0]);
#pragma unroll
        for (int t = 0; t < C::NT; t++) {
            constexpr int NTT = C::NT;
            if (t + 1 < NTT) load_bf(c, t + 1, bf[(t + 1) & 1]);
            int ry, rx;
            C::tap(c, t, ry, rx);
#pragma unroll
            for (int mt = 0; mt < 4; mt++) {
                int x = mt * 16 + (lane & 15);
                int cell = (ry + 1) * 66 + (x + rx + 1);
                int f = (cell + (cell >> 2)) & 3;
                int aa = cell * 32 + (((quad + f) & 3) << 3);
                v8s ah = *(const v8s*)&lA[aa];
                v8s am = *(const v8s*)&lA[APLANE + aa];
                v8s al = *(const v8s*)&lA[2 * APLANE + aa];
#pragma unroll
                for (int nt = 0; nt < 2; nt++) {
                    v4f a0 = acc[mt][nt];
                    a0 = __builtin_amdgcn_mfma_f32_16x16x32_bf16(ah, bf[t & 1][nt][0], a0, 0, 0, 0);
                    a0 = __builtin_amdgcn_mfma_f32_16x16x32_bf16(ah, bf[t & 1][nt][1], a0, 0, 0, 0);
                    a0 = __builtin_amdgcn_mfma_f32_16x16x32_bf16(am, bf[t & 1][nt][0], a0, 0, 0, 0);
                    a0 = __builtin_amdgcn_mfma_f32_16x16x32_bf16(am, bf[t & 1][nt][1], a0, 0, 0, 0);
                    a0 = __builtin_amdgcn_mfma_f32_16x16x32_bf16(ah, bf[t & 1][nt][2], a0, 0, 0, 0);
                    a0 = __builtin_amdgcn_mfma_f32_16x16x32_bf16(al, bf[t & 1][nt][0], a0, 0, 0, 0);
                    acc[mt][nt] = a0;
                }
            }
        }
    }
    // ---- epilogue: pair-plane store, col=lane&15 (oc), row=quad*4+reg (x) --
#pragma unroll
    for (int mt = 0; mt < 4; mt++) {
        int x0 = mt * 16 + quad * 4;
#pragma unroll
        for (int nt = 0; nt < 2; nt++) {
            int oc = (nbase + nt) * 16 + (lane & 15);
            float bv = bias[oc];
            float v0 = acc[mt][nt][0] + bv;
            float v1 = acc[mt][nt][1] + bv;
            float v2 = acc[mt][nt][2] + bv;
            float v3 = acc[mt][nt][3] + bv;
            if constexpr (C::RELU_OUT) {
                v0 = fmaxf(v0, 0.f); v1 = fmaxf(v1, 0.f);
                v2 = fmaxf(v2, 0.f); v3 = fmaxf(v3, 0.f);
            }
            float4 o = make_float4(v0, v1, v2, v3);
            int off = (((n0 + n_img) * 64 + oy) * 64 + (oc >> 1)) * 128 +
                      (oc & 1) * 64 + x0;
            *(float4*)&out[off] = o;
        }
    }
}

// ----- fused residual block, 2 output rows per block (R5/R6 structure) ------
__global__ __launch_bounds__(256) void mfma_res(
    const float* __restrict__ in, const short* __restrict__ repw,
    const float* __restrict__ b1, const short* __restrict__ repp,
    const float* __restrict__ b2, float* __restrict__ out)
{
    constexpr int PLANE_D = 4 * 66 * 16;   // 4224 dwords per limb plane
    constexpr int PLANE_S = 2 * PLANE_D;   // 8448 shorts
    __shared__ __align__(16) short lA[3 * PLANE_S];   // 50688 B

    int tid = threadIdx.x;
    int lane = tid & 63, wv = tid >> 6;
    int n_img = blockIdx.x >> 5;
    int oy0 = (blockIdx.x & 31) << 1;
    int jrow = wv >> 1, xh = wv & 1;

    for (int idx = tid; idx < 3 * 4 * 2 * 16; idx += 256) {
        int plane = idx / 128;
        int rem = idx % 128;
        int rr = rem / 32;
        int hc = (rem >> 4) & 1;
        int d = idx & 15;
        ((unsigned*)lA)[plane * PLANE_D + (rr * 66 + hc * 65) * 16 + d] = 0;
    }

    v4f acc[2][2] = {};     // [mti][nt]
    int Xq = tid & 15, icp = tid >> 4, quad = lane >> 4;

    float pv[32];
    auto issue_loads = [&](int c) {
#pragma unroll
        for (int it = 0; it < 16; it++) {
            int r = it >> 2, xg = it & 3;
            int X = xg * 16 + Xq;
            int Yg = oy0 + r - 1;
            float v0 = 0.f, v1 = 0.f;
            if (Yg >= 0 && Yg < 64) {
                int g = ((n_img * 64 + Yg) * 64 + (c * 16 + icp)) * 128 + X;
                v0 = in[g];
                v1 = in[g + 64];
            }
            pv[2 * it] = v0; pv[2 * it + 1] = v1;
        }
    };

    issue_loads(0);

    for (int c = 0; c < 4; c++) {
        __syncthreads();
#pragma unroll
        for (int it = 0; it < 16; it++) {
            int r = it >> 2, xg = it & 3;
            int X = xg * 16 + Xq;
            float v0 = fmaxf(pv[2 * it], 0.f);       // relu(h)
            float v1 = fmaxf(pv[2 * it + 1], 0.f);
            unsigned short h0, m0, l0, h1, m1, l1;
            limb3(v0, h0, m0, l0);
            limb3(v1, h1, m1, l1);
            int cell = r * 66 + X + 1;
            int f = (cell + (cell >> 2)) & 3;
            int phys = (icp & 3) + 4 * (((icp >> 2) + f) & 3);
            unsigned* pa = (unsigned*)lA + cell * 16 + phys;
            pa[0]           = (unsigned)h0 | ((unsigned)h1 << 16);
            pa[PLANE_D]     = (unsigned)m0 | ((unsigned)m1 << 16);
            pa[2 * PLANE_D] = (unsigned)l0 | ((unsigned)l1 << 16);
        }
        __syncthreads();
        if (c + 1 < 4) issue_loads(c + 1);

        v8s bf[2][2][3];
        auto load_bf = [&](int t, v8s (&dst)[2][3]) {
#pragma unroll
            for (int nt = 0; nt < 2; nt++)
#pragma unroll
                for (int L = 0; L < 3; L++)
                    dst[nt][L] = *(const v8s*)(repw +
                        ((((c * 9 + t) * 3 + L) * 2 + nt) << 9) + (lane << 3));
        };
        load_bf(0, bf[0]);
#pragma unroll
        for (int t = 0; t < 9; t++) {
            if (t + 1 < 9) load_bf(t + 1, bf[(t + 1) & 1]);
            int ry = t / 3 - 1, rx = t % 3 - 1;
#pragma unroll
            for (int mti = 0; mti < 2; mti++) {
                int x = (xh * 2 + mti) * 16 + (lane & 15);
                int cell = (jrow + ry + 1) * 66 + (x + rx + 1);
                int f = (cell + (cell >> 2)) & 3;
                int aa = cell * 32 + (((quad + f) & 3) << 3);
                v8s ah = *(const v8s*)&lA[aa];
                v8s am = *(const v8s*)&lA[PLANE_S + aa];
                v8s al = *(const v8s*)&lA[2 * PLANE_S + aa];
#pragma unroll
                for (int nt = 0; nt < 2; nt++) {
                    v4f a0 = acc[mti][nt];
                    a0 = __builtin_amdgcn_mfma_f32_16x16x32_bf16(ah, bf[t & 1][nt][0], a0, 0, 0, 0);
                    a0 = __builtin_amdgcn_mfma_f32_16x16x32_bf16(ah, bf[t & 1][nt][1], a0, 0, 0, 0);
                    a0 = __builtin_amdgcn_mfma_f32_16x16x32_bf16(am, bf[t & 1][nt][0], a0, 0, 0, 0);
                    a0 = __builtin_amdgcn_mfma_f32_16x16x32_bf16(am, bf[t & 1][nt][1], a0, 0, 0, 0);
                    a0 = __builtin_amdgcn_mfma_f32_16x16x32_bf16(ah, bf[t & 1][nt][2], a0, 0, 0, 0);
                    a0 = __builtin_amdgcn_mfma_f32_16x16x32_bf16(al, bf[t & 1][nt][0], a0, 0, 0, 0);
                    acc[mti][nt] = a0;
                }
            }
        }
    }

    // ===== stage 2: relu(t+b1) limbs -> LDS (A-frag layout, cell=x) =====
    __syncthreads();   // all lA tap-readers done; reuse front of lA
#pragma unroll
    for (int mti = 0; mti < 2; mti++) {
#pragma unroll
        for (int nt = 0; nt < 2; nt++) {
            int ic = nt * 16 + (lane & 15);     // t-channel = GEMM-2 k index
            int icp2 = ic >> 1, hilo = ic & 1;
            float bv = b1[ic];
#pragma unroll
            for (int r = 0; r < 4; r++) {
                int x = (xh * 2 + mti) * 16 + quad * 4 + r;
                float v = fmaxf(acc[mti][nt][r] + bv, 0.f);
                unsigned short h, m, l;
                limb3(v, h, m, l);
                int f = (x + (x >> 2)) & 3;
                int phys = (icp2 & 3) + 4 * (((icp2 >> 2) + f) & 3);
                int sa = x * 32 + phys * 2 + hilo;
                lA[jrow * 6144 + sa]        = (short)h;
                lA[jrow * 6144 + 2048 + sa] = (short)m;
                lA[jrow * 6144 + 4096 + sa] = (short)l;
            }
        }
    }
    __syncthreads();

    // GEMM-2 per row: M=64 (x, mt=wv), N=128 (oc2, nt=0..7), K=32
#pragma unroll
    for (int j = 0; j < 2; j++) {
        v4f a2[8] = {};
        int x = wv * 16 + (lane & 15);
        int f = (x + (x >> 2)) & 3;
        int aa = x * 32 + (((quad + f) & 3) << 3);
        v8s ah = *(const v8s*)&lA[j * 6144 + aa];
        v8s am = *(const v8s*)&lA[j * 6144 + 2048 + aa];
        v8s al = *(const v8s*)&lA[j * 6144 + 4096 + aa];
#pragma unroll
        for (int nt = 0; nt < 8; nt++) {
            v8s bh = *(const v8s*)(repp + ((0 * 8 + nt) << 9) + (lane << 3));
            v8s bm = *(const v8s*)(repp + ((1 * 8 + nt) << 9) + (lane << 3));
            v8s bl = *(const v8s*)(repp + ((2 * 8 + nt) << 9) + (lane << 3));
            v4f a0 = a2[nt];
            a0 = __builtin_amdgcn_mfma_f32_16x16x32_bf16(ah, bh, a0, 0, 0, 0);
            a0 = __builtin_amdgcn_mfma_f32_16x16x32_bf16(ah, bm, a0, 0, 0, 0);
            a0 = __builtin_amdgcn_mfma_f32_16x16x32_bf16(am, bh, a0, 0, 0, 0);
            a0 = __builtin_amdgcn_mfma_f32_16x16x32_bf16(am, bm, a0, 0, 0, 0);
            a0 = __builtin_amdgcn_mfma_f32_16x16x32_bf16(ah, bl, a0, 0, 0, 0);
            a0 = __builtin_amdgcn_mfma_f32_16x16x32_bf16(al, bh, a0, 0, 0, 0);
            a2[nt] = a0;
        }
        // epilogue row j: out = h + t2 + b2   (pair-plane layout)
#pragma unroll
        for (int nt = 0; nt < 8; nt++) {
            int oc = nt * 16 + (lane & 15);
            int x0 = wv * 16 + quad * 4;
            int off = ((n_img * 64 + (oy0 + j)) * 64 + (oc >> 1)) * 128 +
                      (oc & 1) * 64 + x0;
            float4 hv = *(const float4*)&in[off];
            float bv = b2[oc];
            float4 o = make_float4(hv.x + a2[nt][0] + bv, hv.y + a2[nt][1] + bv,
                                   hv.z + a2[nt][2] + bv, hv.w + a2[nt][3] + bv);
            *(float4*)&out[off] = o;
        }
    }
}

// ----- conv1: [8,1,256,256] -> phase-split pair-plane, relu (fp32) ----------
// out addr = (((n*4 + py*2 + px)*64 + y2)*32 + pi)*128 + parity*64 + x2
__global__ __launch_bounds__(256) void conv1_k(
    const float* __restrict__ x, const float* __restrict__ w,
    const float* __restrict__ b, float* __restrict__ out)
{
    int tid = blockIdx.x * 256 + threadIdx.x;     // 131072
    int n   = tid >> 14;
    int rem = tid & 16383;
    int oy  = rem >> 7;
    int ox  = rem & 127;
    int iy0 = oy * 2 - 1, ix0 = ox * 2 - 1;
    const float* xb = x + n * 65536;
    float v[16];
#pragma unroll
    for (int ky = 0; ky < 4; ky++) {
#pragma unroll
        for (int kx = 0; kx < 4; kx++) {
            int iy = iy0 + ky, ix = ix0 + kx;
            bool ok = (iy >= 0) & (iy < 256) & (ix >= 0) & (ix < 256);
            v[ky * 4 + kx] = ok ? xb[iy * 256 + ix] : 0.f;
        }
    }
    int py = oy & 1, y2 = oy >> 1, px = ox & 1, x2 = ox >> 1;
    int obase = (((n * 4 + py * 2 + px) * 64 + y2) * 32) * 128 + x2;
    for (int oc = 0; oc < 64; oc++) {
        float acc = b[oc];
        const float* wp = w + oc * 16;
#pragma unroll
        for (int k = 0; k < 16; k++) acc = fmaf(v[k], wp[k], acc);
        out[obase + (oc >> 1) * 128 + (oc & 1) * 64] = fmaxf(acc, 0.f);
    }
}

// ----- fused 1x1 projection + cosine VQ, 4-way parallel argmax --------------
// 1024 blocks x 256 threads; 64 positions per block.
// Phase 1: wave w computes partial z over icp in [16w,16w+16) (coalesced).
// Phase 2: threads (pl,part) combine partials in fixed order, scan 512 codes
// each, shfl_xor reduce with (max s, tie -> min idx) == global first-max.
__global__ __launch_bounds__(256) void prevq_k(
    const float* __restrict__ h, const float* __restrict__ wpre,
    const float* __restrict__ bpre, const float* __restrict__ cb,
    float* __restrict__ out)
{
    __shared__ float4 en[2048];
    __shared__ float4 zpart[4][64];
    for (int i = threadIdx.x; i < 2048; i += 256) {
        float c0 = cb[i * 4 + 0], c1 = cb[i * 4 + 1];
        float c2 = cb[i * 4 + 2], c3 = cb[i * 4 + 3];
        float nrm = sqrtf(c0 * c0 + c1 * c1 + c2 * c2 + c3 * c3) + 1e-12f;
        en[i] = make_float4(c0 / nrm, c1 / nrm, c2 / nrm, c3 / nrm);
    }

    int t = threadIdx.x;
    // phase 1: per-wave partial z
    {
        int w = t >> 6, pl = t & 63;
        int gpos = blockIdx.x * 64 + pl;
        int n = gpos >> 12, pos = gpos & 4095;
        int y = pos >> 6, xx = pos & 63;
        const float* hb = h + ((n * 64 + y) * 64) * 128 + xx;
        float z0 = 0.f, z1 = 0.f, z2 = 0.f, z3 = 0.f;
        for (int icp = w * 16; icp < w * 16 + 16; icp++) {
            float v0 = fmaxf(hb[icp * 128], 0.f);          // ic = 2*icp
            int ic = 2 * icp;
            z0 = fmaf(v0, wpre[ic],       z0);
            z1 = fmaf(v0, wpre[128 + ic], z1);
            z2 = fmaf(v0, wpre[256 + ic], z2);
            z3 = fmaf(v0, wpre[384 + ic], z3);
            float v1 = fmaxf(hb[icp * 128 + 64], 0.f);     // ic = 2*icp+1
            z0 = fmaf(v1, wpre[ic + 1],       z0);
            z1 = fmaf(v1, wpre[128 + ic + 1], z1);
            z2 = fmaf(v1, wpre[256 + ic + 1], z2);
            z3 = fmaf(v1, wpre[384 + ic + 1], z3);
        }
        zpart[w][pl] = make_float4(z0, z1, z2, z3);
    }
    __syncthreads();

    // phase 2: 4 threads per position
    int part = t & 3, pl = t >> 2;
    int gpos = blockIdx.x * 64 + pl;
    int n = gpos >> 12, pos = gpos & 4095;
    float4 p0 = zpart[0][pl], p1 = zpart[1][pl];
    float4 p2 = zpart[2][pl], p3 = zpart[3][pl];
    float z0 = bpre[0] + p0.x + p1.x + p2.x + p3.x;
    float z1 = bpre[1] + p0.y + p1.y + p2.y + p3.y;
    float z2 = bpre[2] + p0.z + p1.z + p2.z + p3.z;
    float z3 = bpre[3] + p0.w + p1.w + p2.w + p3.w;

    float best = -1e30f;
    int   bidx = part * 512;
    for (int k = part * 512; k < part * 512 + 512; k++) {
        float4 e = en[k];
        float s = z0 * e.x + z1 * e.y + z2 * e.z + z3 * e.w;
        if (s > best) { best = s; bidx = k; }     // local first-max
    }
    // combine 4 parts: max s, tie -> min idx  (== global first-max)
#pragma unroll
    for (int d = 1; d < 4; d <<= 1) {
        float ob = __shfl_xor(best, d);
        int   oi = __shfl_xor(bidx, d);
        if (ob > best || (ob == best && oi < bidx)) { best = ob; bidx = oi; }
    }
    out[(n * 4 + part) * 4096 + pos] = cb[bidx * 4 + part];
}

extern "C" void kernel_launch(void* const* d_in, const int* in_sizes, int n_in,
                              void* d_out, int out_size, void* d_ws, size_t ws_size,
                              hipStream_t stream)
{
    const float* x    = (const float*)d_in[0];
    const float* w1   = (const float*)d_in[1];
    const float* b1   = (const float*)d_in[2];
    const float* w2   = (const float*)d_in[3];
    const float* b2   = (const float*)d_in[4];
    const float* w3   = (const float*)d_in[5];
    const float* b3   = (const float*)d_in[6];
    const float* r1w1 = (const float*)d_in[7];
    const float* r1b1 = (const float*)d_in[8];
    const float* r1w2 = (const float*)d_in[9];
    const float* r1b2 = (const float*)d_in[10];
    const float* r2w1 = (const float*)d_in[11];
    const float* r2b1 = (const float*)d_in[12];
    const float* r2w2 = (const float*)d_in[13];
    const float* r2b2 = (const float*)d_in[14];
    const float* wpre = (const float*)d_in[15];
    const float* bpre = (const float*)d_in[16];
    const float* cb   = (const float*)d_in[17];
    float* out = (float*)d_out;

    float* ws   = (float*)d_ws;
    short* wsS  = (short*)d_ws;
    float* B = ws + B_OFF;
    float* A = ws + A_OFF;

    // one merged repack for all 6 weight tensors
    repack_all_k<<<1408, 256, 0, stream>>>(w2, w3, r1w1, r2w1, r1w2, r2w2, wsS);

    // front end, batch split in halves ping-ponging through A
    conv1_k<<<512, 256, 0, stream>>>(x,               w1, b1, A);
    mfma_conv<CfgConv2><<<512, 256, 0, stream>>>(A, wsS + W2_S, b2, B, 0);
    conv1_k<<<512, 256, 0, stream>>>(x + 8 * 65536,   w1, b1, A);
    mfma_conv<CfgConv2><<<512, 256, 0, stream>>>(A, wsS + W2_S, b2, B, 8);

    // conv3: B -> h @ A
    mfma_conv<CfgConv3><<<1024, 256, 0, stream>>>(B, wsS + W3_S, b3, A, 0);

    // fused residual blocks (ping-pong A->B->A), 2 rows/block
    mfma_res<<<512, 256, 0, stream>>>(A, wsS + WR1_S, r1b1, wsS + WP1_S, r1b2, B);
    mfma_res<<<512, 256, 0, stream>>>(B, wsS + WR2_S, r2b1, wsS + WP2_S, r2b2, A);

    // 1x1 projection + vector quantization
    prevq_k<<<1024, 256, 0, stream>>>(A, wpre, bpre, cb, out);
}